// Round 10
// baseline (699.006 us; speedup 1.0000x reference)
//
#include <hip/hip_runtime.h>

typedef __attribute__((ext_vector_type(8))) short short8;
typedef __attribute__((ext_vector_type(4))) float f32x4;
typedef unsigned int uint;
typedef unsigned short ushort;

#define PLF 524288   // 1024*512 elements per activation plane

__device__ __forceinline__ ushort f2bf(float f) {
  uint u = __float_as_uint(f);
  u += 0x7FFF + ((u >> 16) & 1);   // RNE
  return (ushort)(u >> 16);
}
__device__ __forceinline__ float bf2f(ushort h) {
  return __uint_as_float(((uint)h) << 16);
}
__device__ __forceinline__ int swzf(int r) { return ((r & 3) ^ ((r >> 2) & 3)); }

#define GLOAD16(gp, lp)                                          \
  __builtin_amdgcn_global_load_lds(                              \
      (const __attribute__((address_space(1))) void*)(gp),       \
      (__attribute__((address_space(3))) void*)(lp), 16, 0, 0)

// ---------------------------------------------------------------------------
// MFMA GEMM: C[m][n] = alpha * sum_k A[m][k] * B[n][k]  (both row-major-K)
// 3-buffer LDS pipeline, counted vmcnt (BCVT=0). KS: K-split factor — z is
// (plane, split); each split does K/KS and atomicAdds fp32 C (base pre-set).
// Per-z offsets: off = (z/Div)*S1 + (z%Mod)*S2 (element units).
// ROPE: rotary embedding in epilogue (row = position, col = feature).
// ---------------------------------------------------------------------------
template <int CDT, int BETA, int RELU2, int MFAST, int BCVT, int ROPE, int KS>
__global__ __launch_bounds__(256) void mm_kernel(
    const void* __restrict__ Av, const void* __restrict__ Bv, void* __restrict__ Cv,
    int K, int lda, int ldb, int ldc,
    int aDiv, int aMod, long long aS1, long long aS2,
    int bDiv, int bMod, long long bS1, long long bS2,
    int cDiv, int cMod, long long cS1, long long cS2, float alpha)
{
  __shared__ char lds[49152];   // 3 bufs x (A 8KB | B 8KB)
  const int nx = gridDim.x, ny = gridDim.y;
  const int nwg = nx * ny * (int)gridDim.z;
  const int o = ((int)blockIdx.z * ny + blockIdx.y) * nx + blockIdx.x;
  const int qd = nwg >> 3, rm = nwg & 7, xcd = o & 7, rot = o >> 3;
  const int wflat = (xcd < rm ? xcd * (qd + 1) : rm * (qd + 1) + (xcd - rm) * qd) + rot;
  int bx, by, bz;
  if (MFAST) { by = wflat % ny; int t2 = wflat / ny; bx = t2 % nx; bz = t2 / nx; }
  else       { bx = wflat % nx; int t2 = wflat / nx; by = t2 % ny; bz = t2 / ny; }
  int kb = 0;
  if (KS > 1) { kb = (bz % KS) * (K / KS); bz /= KS; }
  const int KH = K / KS;
  const int tid = threadIdx.x;
  const long long aOff = (long long)(bz / aDiv) * aS1 + (long long)(bz % aMod) * aS2;
  const long long bOff = (long long)(bz / bDiv) * bS1 + (long long)(bz % bMod) * bS2;
  const long long cOff = (long long)(bz / cDiv) * cS1 + (long long)(bz % cMod) * cS2;
  const int m0 = by * 128, n0 = bx * 128;
  const int lane = tid & 63, wid = tid >> 6;
  const int MOFF = (wid >> 1) * 64, NOFF = (wid & 1) * 64;
  const int u = lane & 15, g = lane >> 4;
  const int sr0 = tid >> 2, sslot = tid & 3;
  const ushort* Ap = (const ushort*)Av + aOff + kb;
  const ushort* Bp = (const ushort*)Bv + bOff + kb;
  const float*  Bf = (const float*)Bv + bOff + kb;

#define STAGE(buf, kt)                                                         \
  {                                                                            \
    _Pragma("unroll")                                                          \
    for (int half = 0; half < 2; ++half) {                                     \
      const int r = sr0 + 64 * half;                                           \
      const int ss = sslot ^ swzf(r);                                          \
      GLOAD16(Ap + (long long)(m0 + r) * lda + (kt) + ss * 8,                  \
              &lds[(buf) * 16384] + wid * 1024 + half * 4096);                 \
      if (BCVT == 0) {                                                         \
        GLOAD16(Bp + (long long)(n0 + r) * ldb + (kt) + ss * 8,                \
                &lds[(buf) * 16384 + 8192] + wid * 1024 + half * 4096);        \
      } else {                                                                 \
        const float* srcB = Bf + (long long)(n0 + r) * ldb + (kt) + ss * 8;    \
        float4 x0 = *(const float4*)srcB;                                      \
        float4 x1 = *(const float4*)(srcB + 4);                                \
        short8 h;                                                              \
        h[0] = (short)f2bf(x0.x); h[1] = (short)f2bf(x0.y);                    \
        h[2] = (short)f2bf(x0.z); h[3] = (short)f2bf(x0.w);                    \
        h[4] = (short)f2bf(x1.x); h[5] = (short)f2bf(x1.y);                    \
        h[6] = (short)f2bf(x1.z); h[7] = (short)f2bf(x1.w);                    \
        *(short8*)(&lds[(buf) * 16384 + 8192] + r * 64 + sslot * 16) = h;      \
      }                                                                        \
    }                                                                          \
  }

  f32x4 acc[4][4];
#pragma unroll
  for (int i = 0; i < 4; ++i)
#pragma unroll
    for (int j = 0; j < 4; ++j) acc[i][j] = (f32x4){0.f, 0.f, 0.f, 0.f};

  const int T = KH >> 5;
  STAGE(0, 0);
  if (T > 1) STAGE(1, 32);
  int rb = 0, sb = 2;
  for (int t = 0; t < T; ++t) {
    if (BCVT == 0) {
      if (t + 1 < T) { asm volatile("s_waitcnt vmcnt(4)" ::: "memory"); }
      else           { asm volatile("s_waitcnt vmcnt(0)" ::: "memory"); }
    } else {
      asm volatile("s_waitcnt vmcnt(0) lgkmcnt(0)" ::: "memory");
    }
    __builtin_amdgcn_s_barrier();
    __builtin_amdgcn_sched_barrier(0);
    asm volatile("" ::: "memory");
    if (t + 2 < T) STAGE(sb, (t + 2) * 32);
    const char* Abuf = &lds[rb * 16384];
    const char* Bbuf = &lds[rb * 16384 + 8192];
    short8 af[4], bfr[4];
#pragma unroll
    for (int mi = 0; mi < 4; ++mi) {
      const int r = MOFF + mi * 16 + u;
      af[mi] = *(const short8*)(Abuf + r * 64 + ((g ^ swzf(r)) * 16));
    }
#pragma unroll
    for (int ni = 0; ni < 4; ++ni) {
      const int r = NOFF + ni * 16 + u;
      bfr[ni] = *(const short8*)(Bbuf + r * 64 + ((g ^ swzf(r)) * 16));
    }
    __builtin_amdgcn_s_setprio(1);
#pragma unroll
    for (int mi = 0; mi < 4; ++mi)
#pragma unroll
      for (int ni = 0; ni < 4; ++ni)
        acc[mi][ni] = __builtin_amdgcn_mfma_f32_16x16x32_bf16(af[mi], bfr[ni], acc[mi][ni], 0, 0, 0);
    __builtin_amdgcn_s_setprio(0);
    rb = (rb == 2) ? 0 : rb + 1;
    sb = (sb == 2) ? 0 : sb + 1;
  }
#undef STAGE

#pragma unroll
  for (int mi = 0; mi < 4; ++mi)
#pragma unroll
    for (int ni = 0; ni < 4; ++ni)
#pragma unroll
      for (int q = 0; q < 4; ++q) {
        const int row = m0 + MOFF + mi * 16 + g * 4 + q;
        const int col = n0 + NOFF + ni * 16 + u;
        float v = acc[mi][ni][q] * alpha;
        if (CDT == 0) {
          float* cp = (float*)Cv + cOff + (long long)row * ldc + col;
          if (KS > 1) {
            atomicAdd(cp, v);
          } else {
            if (BETA) v += *cp;
            *cp = v;
          }
        } else {
          if (ROPE) {
            const int j = (col & 127) >> 1;
            const float infr = __expf((float)j * (-9.210340371976184f / 64.f));
            float sn, cs;
            __sincosf((float)row * infr, &sn, &cs);
            const float part = __shfl_xor(v, 1);
            v = (col & 1) ? fmaf(part, sn, v * cs) : fmaf(-part, sn, v * cs);
          }
          if (RELU2) { v = fmaxf(v, 0.f); v = v * v; }
          ((ushort*)Cv)[cOff + (long long)row * ldc + col] = f2bf(v);
        }
      }
}

// ---------------------------------------------------------------------------
// Fused flash attention (round-7 structure + setprio on MFMA clusters).
// ---------------------------------------------------------------------------
__global__ __launch_bounds__(256) void fattn_kernel(
    const ushort* __restrict__ Qg, const ushort* __restrict__ Kg,
    const ushort* __restrict__ Vg, ushort* __restrict__ Og)
{
  __shared__ char lds[73728];
  const int hb = blockIdx.y, pl = hb >> 3, h = hb & 7;
  const int q0 = blockIdx.x * 64;
  const int tid = threadIdx.x, lane = tid & 63, wv = tid >> 6;
  const int u = lane & 15, g = lane >> 4;
  const ushort* Qh = Qg + (size_t)pl * PLF + h * 128;
  const ushort* Kh = Kg + (size_t)pl * PLF + h * 128;
  const ushort* Vh = Vg + (size_t)pl * PLF + (size_t)(h * 128) * 512;
  ushort* Oh = Og + (size_t)pl * PLF + h * 128;

  short8 qf[4];
  const int qrow = q0 + wv * 16 + u;
#pragma unroll
  for (int dc = 0; dc < 4; ++dc)
    qf[dc] = *(const short8*)(Qh + (size_t)qrow * 1024 + dc * 32 + g * 8);

#define STAGE_KV(buf, kt)                                                     \
  {                                                                           \
    _Pragma("unroll")                                                         \
    for (int it = 0; it < 4; ++it) {                                          \
      const int off = tid * 16 + it * 4096;                                   \
      const int krow = off >> 8, kslot = (off >> 4) & 15;                     \
      GLOAD16(Kh + (size_t)((kt) * 64 + krow) * 1024 +                        \
                  ((kslot ^ ((krow & 7) << 1)) * 8),                          \
              &lds[(buf) * 16384] + off);                                     \
      const int vrow = off >> 7, vslot = (off >> 4) & 7;                      \
      GLOAD16(Vh + (size_t)vrow * 512 + (kt) * 64 + ((vslot ^ (vrow & 7)) * 8), \
              &lds[32768 + (buf) * 16384] + off);                             \
    }                                                                         \
  }

  f32x4 oacc[8];
#pragma unroll
  for (int i = 0; i < 8; ++i) oacc[i] = (f32x4){0.f, 0.f, 0.f, 0.f};
  float m_run = -3.0e38f, l_run = 0.f;

  STAGE_KV(0, 0);
  asm volatile("s_waitcnt vmcnt(0)" ::: "memory");
  __syncthreads();
  int cur = 0;
  for (int kt = 0; kt < 8; ++kt) {
    if (kt + 1 < 8) STAGE_KV(cur ^ 1, kt + 1);
    f32x4 sacc[4];
#pragma unroll
    for (int kn = 0; kn < 4; ++kn) sacc[kn] = (f32x4){0.f, 0.f, 0.f, 0.f};
    __builtin_amdgcn_s_setprio(1);
#pragma unroll
    for (int kn = 0; kn < 4; ++kn) {
      const int r = kn * 16 + u;
      const char* kb = &lds[cur * 16384] + r * 256;
#pragma unroll
      for (int dc = 0; dc < 4; ++dc) {
        short8 kf = *(const short8*)(kb + (((dc * 4 + g) ^ ((u & 7) << 1)) * 16));
        sacc[kn] = __builtin_amdgcn_mfma_f32_16x16x32_bf16(kf, qf[dc], sacc[kn], 0, 0, 0);
      }
    }
    __builtin_amdgcn_s_setprio(0);
    float pm = -3.0e38f;
#pragma unroll
    for (int kn = 0; kn < 4; ++kn)
#pragma unroll
      for (int r = 0; r < 4; ++r) {
        sacc[kn][r] *= 0.03125f;
        pm = fmaxf(pm, sacc[kn][r]);
      }
    pm = fmaxf(pm, __shfl_xor(pm, 16));
    pm = fmaxf(pm, __shfl_xor(pm, 32));
    const float m_new = fmaxf(m_run, pm);
    const float es = __expf(m_run - m_new);
    float psum = 0.f;
    uint pw[4][2];
#pragma unroll
    for (int kn = 0; kn < 4; ++kn) {
      float p0 = __expf(sacc[kn][0] - m_new);
      float p1 = __expf(sacc[kn][1] - m_new);
      float p2 = __expf(sacc[kn][2] - m_new);
      float p3 = __expf(sacc[kn][3] - m_new);
      psum += (p0 + p1) + (p2 + p3);
      pw[kn][0] = (uint)f2bf(p0) | ((uint)f2bf(p1) << 16);
      pw[kn][1] = (uint)f2bf(p2) | ((uint)f2bf(p3) << 16);
    }
    psum += __shfl_xor(psum, 16);
    psum += __shfl_xor(psum, 32);
    l_run = l_run * es + psum;
    m_run = m_new;
    char* pb = &lds[65536 + wv * 2048] + u * 128 + (g & 1) * 8;
#pragma unroll
    for (int kn = 0; kn < 4; ++kn)
      *(uint2*)(pb + (((2 * kn + (g >> 1)) ^ (u & 7)) * 16)) =
          make_uint2(pw[kn][0], pw[kn][1]);
    float es_o[4];
#pragma unroll
    for (int r = 0; r < 4; ++r) es_o[r] = __shfl(es, g * 4 + r);
#pragma unroll
    for (int nd = 0; nd < 8; ++nd)
#pragma unroll
      for (int r = 0; r < 4; ++r) oacc[nd][r] *= es_o[r];
    const char* prd = &lds[65536 + wv * 2048] + u * 128;
    short8 pf[2];
#pragma unroll
    for (int kc = 0; kc < 2; ++kc)
      pf[kc] = *(const short8*)(prd + (((kc * 4 + g) ^ (u & 7)) * 16));
    __builtin_amdgcn_s_setprio(1);
#pragma unroll
    for (int nd = 0; nd < 8; ++nd) {
      const int vr = nd * 16 + u;
      const char* vb = &lds[32768 + cur * 16384] + vr * 128;
#pragma unroll
      for (int kc = 0; kc < 2; ++kc) {
        short8 vf = *(const short8*)(vb + (((kc * 4 + g) ^ (u & 7)) * 16));
        oacc[nd] = __builtin_amdgcn_mfma_f32_16x16x32_bf16(pf[kc], vf, oacc[nd], 0, 0, 0);
      }
    }
    __builtin_amdgcn_s_setprio(0);
    asm volatile("s_waitcnt vmcnt(0)" ::: "memory");
    __syncthreads();
    cur ^= 1;
  }
#undef STAGE_KV
  const float inv_l = 1.f / l_run;
  float inv_o[4];
#pragma unroll
  for (int r = 0; r < 4; ++r) inv_o[r] = __shfl(inv_l, g * 4 + r);
#pragma unroll
  for (int nd = 0; nd < 8; ++nd)
#pragma unroll
    for (int r = 0; r < 4; ++r) {
      const int row = q0 + wv * 16 + g * 4 + r;
      Oh[(size_t)row * 1024 + nd * 16 + u] = f2bf(oacc[nd][r] * inv_o[r]);
    }
}

// ---------------- fp32 -> bf16 weight conversion (8 elem/thread) ------------
__global__ __launch_bounds__(256) void cvt_kernel(
    const float4* __restrict__ s, short8* __restrict__ d)
{
  const int i = blockIdx.x * 256 + threadIdx.x;
  const float4 a = s[2 * i], b = s[2 * i + 1];
  short8 h;
  h[0] = (short)f2bf(a.x); h[1] = (short)f2bf(a.y);
  h[2] = (short)f2bf(a.z); h[3] = (short)f2bf(a.w);
  h[4] = (short)f2bf(b.x); h[5] = (short)f2bf(b.y);
  h[6] = (short)f2bf(b.z); h[7] = (short)f2bf(b.w);
  d[i] = h;
}

// ---------------------------------------------------------------------------
// conv 3x3 SAME on [512 w][F f] planes; 8 f-outputs x 4 out-channels/thread.
// ---------------------------------------------------------------------------
template <int CIN>
__global__ __launch_bounds__(256) void conv4c_kernel(
    const ushort* __restrict__ in, const float* __restrict__ wt,
    const float* __restrict__ bias, ushort* __restrict__ outp, int log2F)
{
  const int idx = blockIdx.x * 256 + threadIdx.x;
  const int F8m = (1 << (log2F - 3)) - 1;
  const int f8 = idx & F8m;
  const int w = (idx >> (log2F - 3)) & 511;
  const int bb = idx >> (log2F + 6);
  const int f0 = f8 << 3;
  float acc[4][8];
#pragma unroll
  for (int co = 0; co < 4; ++co) {
    const float bv = bias[co];
#pragma unroll
    for (int j = 0; j < 8; ++j) acc[co][j] = bv;
  }
  const bool lok = f8 > 0, rok = f8 < F8m;
#pragma unroll
  for (int ci = 0; ci < CIN; ++ci) {
    const ushort* base = in + (((size_t)(bb * CIN + ci)) << (log2F + 9));
#pragma unroll
    for (int dxw = 0; dxw < 3; ++dxw) {
      const int w2 = w + dxw - 1;
      if (w2 < 0 || w2 > 511) continue;
      const ushort* rp = base + ((size_t)w2 << log2F) + f0;
      const short8 cen = *(const short8*)rp;
      float xv[10];
      xv[0] = lok ? bf2f(rp[-1]) : 0.f;
#pragma unroll
      for (int j = 0; j < 8; ++j) xv[j + 1] = bf2f((ushort)cen[j]);
      xv[9] = rok ? bf2f(rp[8]) : 0.f;
#pragma unroll
      for (int co = 0; co < 4; ++co) {
        const float* wp = wt + (co * CIN + ci) * 9;
        const float k0 = wp[dxw], k1 = wp[3 + dxw], k2 = wp[6 + dxw];
#pragma unroll
        for (int j = 0; j < 8; ++j)
          acc[co][j] += k0 * xv[j] + k1 * xv[j + 1] + k2 * xv[j + 2];
      }
    }
  }
#pragma unroll
  for (int co = 0; co < 4; ++co) {
    short8 o;
#pragma unroll
    for (int j = 0; j < 8; ++j) o[j] = (short)f2bf(acc[co][j]);
    *(short8*)(outp + (((size_t)(bb * 4 + co)) << (log2F + 9)) + ((size_t)w << log2F) + f0) = o;
  }
}

// ---------------------------------------------------------------------------
// q/k/v merged conv: reads XN once, computes 12 output channels (3 proj x 4c).
// ---------------------------------------------------------------------------
__global__ __launch_bounds__(256) void conv12c_kernel(
    const ushort* __restrict__ in,
    const float* __restrict__ wq, const float* __restrict__ wk, const float* __restrict__ wv,
    const float* __restrict__ bq, const float* __restrict__ bk, const float* __restrict__ bv,
    ushort* __restrict__ outp, int nPl)
{
  const int idx = blockIdx.x * 256 + threadIdx.x;
  const int f8 = idx & 127;
  const int w = (idx >> 7) & 511;
  const int bb = idx >> 16;
  const int f0 = f8 << 3;
  const float* wsel[3] = {wq, wk, wv};
  float acc[12][8];
#pragma unroll
  for (int co = 0; co < 4; ++co) {
    const float b0 = bq[co], b1 = bk[co], b2 = bv[co];
#pragma unroll
    for (int j = 0; j < 8; ++j) {
      acc[co][j] = b0; acc[4 + co][j] = b1; acc[8 + co][j] = b2;
    }
  }
  const bool lok = f8 > 0, rok = f8 < 127;
#pragma unroll
  for (int ci = 0; ci < 4; ++ci) {
    const ushort* base = in + (((size_t)(bb * 4 + ci)) << 19);
#pragma unroll
    for (int dxw = 0; dxw < 3; ++dxw) {
      const int w2 = w + dxw - 1;
      if (w2 < 0 || w2 > 511) continue;
      const ushort* rp = base + ((size_t)w2 << 10) + f0;
      const short8 cen = *(const short8*)rp;
      float xv[10];
      xv[0] = lok ? bf2f(rp[-1]) : 0.f;
#pragma unroll
      for (int j = 0; j < 8; ++j) xv[j + 1] = bf2f((ushort)cen[j]);
      xv[9] = rok ? bf2f(rp[8]) : 0.f;
#pragma unroll
      for (int pj = 0; pj < 3; ++pj)
#pragma unroll
        for (int co = 0; co < 4; ++co) {
          const float* wp = wsel[pj] + (co * 4 + ci) * 9;
          const float k0 = wp[dxw], k1 = wp[3 + dxw], k2 = wp[6 + dxw];
#pragma unroll
          for (int j = 0; j < 8; ++j)
            acc[pj * 4 + co][j] += k0 * xv[j] + k1 * xv[j + 1] + k2 * xv[j + 2];
        }
    }
  }
#pragma unroll
  for (int pj = 0; pj < 3; ++pj)
#pragma unroll
    for (int co = 0; co < 4; ++co) {
      short8 o;
#pragma unroll
      for (int j = 0; j < 8; ++j) o[j] = (short)f2bf(acc[pj * 4 + co][j]);
      *(short8*)(outp + (((size_t)(pj * nPl + bb * 4 + co)) << 19) +
                 ((size_t)w << 10) + f0) = o;
    }
}

// ---------------- layernorm over f (rows of 1024), H fp32 -> XN bf16 --------
__global__ __launch_bounds__(256) void ln_kernel(
    const float* __restrict__ H, const float* __restrict__ gam,
    const float* __restrict__ bet, ushort* __restrict__ XN)
{
  const int wid = threadIdx.x >> 6, lane = threadIdx.x & 63;
  const int row = blockIdx.x * 4 + wid;
  const int c = (row >> 9) & 3;
  const float* xp = H + (size_t)row * 1024;
  float4 v[4];
  float s = 0.f, q = 0.f;
#pragma unroll
  for (int p = 0; p < 4; ++p) {
    v[p] = *(const float4*)(xp + p * 256 + lane * 4);
    s += v[p].x + v[p].y + v[p].z + v[p].w;
    q += v[p].x * v[p].x + v[p].y * v[p].y + v[p].z * v[p].z + v[p].w * v[p].w;
  }
#pragma unroll
  for (int o = 32; o > 0; o >>= 1) { s += __shfl_xor(s, o); q += __shfl_xor(q, o); }
  const float mu = s * (1.f / 1024.f);
  const float var = q * (1.f / 1024.f) - mu * mu;
  const float rs = rsqrtf(var + 1e-5f);
  ushort* op = XN + (size_t)row * 1024;
  const float* gp = gam + c * 1024;
  const float* bp = bet + c * 1024;
#pragma unroll
  for (int p = 0; p < 4; ++p) {
    const int f = p * 256 + lane * 4;
    float4 g4 = *(const float4*)(gp + f);
    float4 b4 = *(const float4*)(bp + f);
    ushort4 o4;
    o4.x = f2bf((v[p].x - mu) * rs * g4.x + b4.x);
    o4.y = f2bf((v[p].y - mu) * rs * g4.y + b4.y);
    o4.z = f2bf((v[p].z - mu) * rs * g4.z + b4.z);
    o4.w = f2bf((v[p].w - mu) * rs * g4.w + b4.w);
    *(ushort4*)(op + f) = o4;
  }
}

// ---- transpose-in: x fp32 [f][w] -> XT bf16 [w][f]; also copy x -> out -----
__global__ __launch_bounds__(256) void tin_kernel(
    const float* __restrict__ x, ushort* __restrict__ XT,
    float* __restrict__ outp, int planeOff)
{
  __shared__ float t[32][33];
  const int f0 = blockIdx.x * 32, w0 = blockIdx.y * 32;
  const int z = blockIdx.z;
  const int tx = threadIdx.x & 31, ty = threadIdx.x >> 5;
  const int gpl = planeOff + z;
  const int b = gpl >> 3, ch = gpl & 7;
  const float* src = x + (size_t)gpl * PLF;
  float* dst0 = outp + (size_t)(b * 12 + ch) * PLF;
#pragma unroll
  for (int r = 0; r < 32; r += 8) {
    const size_t off = (size_t)(f0 + r + ty) * 512 + w0 + tx;
    const float v = src[off];
    t[r + ty][tx] = v;
    dst0[off] = v;
  }
  __syncthreads();
  ushort* dst = XT + (size_t)z * PLF;
#pragma unroll
  for (int r = 0; r < 32; r += 8) dst[(size_t)(w0 + r + ty) * 1024 + f0 + tx] = f2bf(t[tx][r + ty]);
}

// ---------------- transpose-out: H fp32 [w][f] -> out[b][8+c][f][w] ---------
__global__ __launch_bounds__(256) void tout_kernel(
    const float* __restrict__ H, float* __restrict__ out, int b0)
{
  __shared__ float t[32][33];
  const int w0 = blockIdx.x * 32, f0 = blockIdx.y * 32;
  const int p = blockIdx.z;
  const int b = b0 + (p >> 2), c = p & 3;
  const int tx = threadIdx.x & 31, ty = threadIdx.x >> 5;
  const float* src = H + (size_t)p * PLF;
#pragma unroll
  for (int r = 0; r < 32; r += 8) t[r + ty][tx] = src[(size_t)(w0 + r + ty) * 1024 + f0 + tx];
  __syncthreads();
  float* dst = out + (size_t)(b * 12 + 8 + c) * PLF;
#pragma unroll
  for (int r = 0; r < 32; r += 8) dst[(size_t)(f0 + r + ty) * 512 + w0 + tx] = t[tx][r + ty];
}

// ---------------------------------------------------------------------------
extern "C" void kernel_launch(void* const* d_in, const int* in_sizes, int n_in,
                              void* d_out, int out_size, void* d_ws, size_t ws_size,
                              hipStream_t stream)
{
  const float* x        = (const float*)d_in[0];
  const float* embed_cw = (const float*)d_in[1];
  const float* embed_cb = (const float*)d_in[2];
  const float* embed_pw = (const float*)d_in[3];
  const float* n1g      = (const float*)d_in[4];
  const float* n1b      = (const float*)d_in[5];
  const float* q_cw     = (const float*)d_in[6];
  const float* q_cb     = (const float*)d_in[7];
  const float* q_pw     = (const float*)d_in[8];
  const float* k_cw     = (const float*)d_in[9];
  const float* k_cb     = (const float*)d_in[10];
  const float* k_pw     = (const float*)d_in[11];
  const float* v_cw     = (const float*)d_in[12];
  const float* v_cb     = (const float*)d_in[13];
  const float* v_pw     = (const float*)d_in[14];
  const float* o_cw     = (const float*)d_in[15];
  const float* o_cb     = (const float*)d_in[16];
  const float* o_pw     = (const float*)d_in[17];
  const float* n2g      = (const float*)d_in[18];
  const float* n2b      = (const float*)d_in[19];
  const float* f1_cw    = (const float*)d_in[20];
  const float* f1_cb    = (const float*)d_in[21];
  const float* f1_pw    = (const float*)d_in[22];
  const float* f2_cw    = (const float*)d_in[23];
  const float* f2_cb    = (const float*)d_in[24];
  const float* f2_pw    = (const float*)d_in[25];
  float* out = (float*)d_out;

  const size_t perB = 50331648ull;
  const int N = (ws_size >= 4 * perB) ? 4 : (ws_size >= 2 * perB) ? 2 : 1;
  const int nP = 4 * N;

  // layout: Hf | XT | XN | Qb | Kb | CT | Vb | SfPb
  char* base = (char*)d_ws;
  float*  Hf = (float*)base;                                    // N*8388608 B
  ushort* XT = (ushort*)(base + (size_t)N * 8388608);           // N*8388608 B
  ushort* XN = (ushort*)((char*)XT + (size_t)N * 8388608);      // N*4194304 B
  ushort* Qb = (ushort*)((char*)XN + (size_t)N * 4194304);
  ushort* Kb = (ushort*)((char*)Qb + (size_t)N * 4194304);      // adjacent to Qb!
  ushort* CT = (ushort*)((char*)Kb + (size_t)N * 4194304);
  ushort* Vb = (ushort*)((char*)CT + (size_t)N * 4194304);
  ushort* SfPb = (ushort*)((char*)Vb + (size_t)N * 4194304);    // N*12582912 B
  ushort* CT3 = SfPb;                  // q/k/v conv outputs, 3*nP planes
  ushort* W8  = SfPb;                  // 8.4MB bf16 weight slot (embed/o/v)
  ushort* WQK = XT;                    // 16.8MB qk weights (N>=2)
  ushort* MID = XT;                    // ffn1 out (XT..Qb span)
  ushort* f1w = Vb;                    // ffn1 weight (Vb..SfPb span, N>=2)
  ushort* F2C = Vb;                    // ffn2 conv out (Vb..SfPb span)
  ushort* f2w = XT;                    // ffn2 weight (XT..Qb span, N>=2)

  const long long W1 = 1048576;
  const long long W4 = 4194304;
  const long long M1 = 2097152;
  const long long CH3 = (long long)nP * PLF;   // CT3 chunk stride
  const int GCc1 = N * 256;
  const int GCc4 = N * 1024;

  for (int b0 = 0; b0 < 4; b0 += N) {
    // --- input transpose + x copy to out ---
    tin_kernel<<<dim3(32, 16, 8 * N), 256, 0, stream>>>(x, XT, out, b0 * 8);
    // --- embed ---
    conv4c_kernel<8><<<GCc1, 256, 0, stream>>>(XT, embed_cw, embed_cb, CT, 10);
    cvt_kernel<<<2048, 256, 0, stream>>>((const float4*)embed_pw, (short8*)W8);
    mm_kernel<0, 0, 0, 0, 0, 0, 1><<<dim3(8, 4, nP), 256, 0, stream>>>(
        CT, W8, Hf, 1024, 1024, 1024, 1024,
        1, 1, PLF, 0, 4, 4, 0, W1, 1, 1, PLF, 0, 1.f);
    // --- LN1 ---
    ln_kernel<<<nP * 128, 256, 0, stream>>>(Hf, n1g, n1b, XN);
    // --- merged q/k/v conv ---
    conv12c_kernel<<<GCc1, 256, 0, stream>>>(XN, q_cw, k_cw, v_cw,
                                             q_cb, k_cb, v_cb, CT3, nP);
    // --- q+k projection (RoPE fused into epilogue) ---
    if (N >= 2) {
      cvt_kernel<<<2048, 256, 0, stream>>>((const float4*)q_pw, (short8*)WQK);
      cvt_kernel<<<2048, 256, 0, stream>>>((const float4*)k_pw, (short8*)(WQK) + 524288);
      mm_kernel<1, 0, 0, 0, 0, 1, 1><<<dim3(8, 4, 2 * nP), 256, 0, stream>>>(
          CT3, WQK, Qb, 1024, 1024, 1024, 1024,
          1, 1, PLF, 0, nP, 4, 4 * W1, W1, 1, 1, PLF, 0, 1.f);
    } else {
      mm_kernel<1, 0, 0, 0, 1, 1, 1><<<dim3(8, 4, nP), 256, 0, stream>>>(
          CT3, q_pw, Qb, 1024, 1024, 1024, 1024,
          1, 1, PLF, 0, 4, 4, 0, W1, 1, 1, PLF, 0, 1.f);
      mm_kernel<1, 0, 0, 0, 1, 1, 1><<<dim3(8, 4, nP), 256, 0, stream>>>(
          CT3 + CH3, k_pw, Kb, 1024, 1024, 1024, 1024,
          1, 1, PLF, 0, 4, 4, 0, W1, 1, 1, PLF, 0, 1.f);
    }
    // --- v projection (V stored [f][w]); W8 clobbers CT3 chunk0 (dead) ---
    cvt_kernel<<<2048, 256, 0, stream>>>((const float4*)v_pw, (short8*)W8);
    mm_kernel<1, 0, 0, 0, 0, 0, 1><<<dim3(4, 8, nP), 256, 0, stream>>>(
        W8, CT3 + 2 * CH3, Vb, 1024, 1024, 1024, 512,
        4, 4, 0, W1, 1, 1, PLF, 0, 1, 1, PLF, 0, 1.f);
    // --- fused flash attention (O overwrites Q) ---
    fattn_kernel<<<dim3(8, nP * 8), 256, 0, stream>>>(Qb, Kb, Vb, Qb);
    // --- o projection: K-split x2, atomicAdd into Hf (base = embed) ---
    conv4c_kernel<4><<<GCc1, 256, 0, stream>>>(Qb, o_cw, o_cb, CT, 10);
    cvt_kernel<<<2048, 256, 0, stream>>>((const float4*)o_pw, (short8*)W8);
    mm_kernel<0, 0, 0, 0, 0, 0, 2><<<dim3(8, 4, 2 * nP), 256, 0, stream>>>(
        CT, W8, Hf, 1024, 1024, 1024, 1024,
        1, 1, PLF, 0, 4, 4, 0, W1, 1, 1, PLF, 0, 1.f);
    // --- LN2 ---
    ln_kernel<<<nP * 128, 256, 0, stream>>>(Hf, n2g, n2b, XN);
    // --- ffn1 (+fused squared relu) ---
    conv4c_kernel<4><<<GCc1, 256, 0, stream>>>(XN, f1_cw, f1_cb, CT, 10);
    if (N >= 2) {
      cvt_kernel<<<8192, 256, 0, stream>>>((const float4*)f1_pw, (short8*)f1w);
      mm_kernel<1, 0, 1, 1, 0, 0, 1><<<dim3(32, 4, nP), 256, 0, stream>>>(
          CT, f1w, MID, 1024, 1024, 1024, 4096,
          1, 1, PLF, 0, 4, 4, 0, W4, 1, 1, M1, 0, 1.f);
    } else {
      mm_kernel<1, 0, 1, 1, 1, 0, 1><<<dim3(32, 4, nP), 256, 0, stream>>>(
          CT, f1_pw, MID, 1024, 1024, 1024, 4096,
          1, 1, PLF, 0, 4, 4, 0, W4, 1, 1, M1, 0, 1.f);
    }
    // --- ffn2 conv (F=4096) then pw K-split x2 atomicAdd into Hf ---
    conv4c_kernel<4><<<GCc4, 256, 0, stream>>>(MID, f2_cw, f2_cb, F2C, 12);
    if (N >= 2) {
      cvt_kernel<<<8192, 256, 0, stream>>>((const float4*)f2_pw, (short8*)f2w);
      mm_kernel<0, 0, 0, 0, 0, 0, 2><<<dim3(8, 4, 2 * nP), 256, 0, stream>>>(
          F2C, f2w, Hf, 4096, 4096, 4096, 1024,
          1, 1, M1, 0, 4, 4, 0, W4, 1, 1, PLF, 0, 1.f);
    } else {
      mm_kernel<0, 1, 0, 0, 1, 0, 1><<<dim3(8, 4, nP), 256, 0, stream>>>(
          F2C, f2_pw, Hf, 4096, 4096, 4096, 1024,
          1, 1, M1, 0, 4, 4, 0, W4, 1, 1, PLF, 0, 1.f);
    }
    // --- output transpose ---
    tout_kernel<<<dim3(16, 32, nP), 256, 0, stream>>>(Hf, out, b0);
  }
}

// Round 11
// 659.661 us; speedup vs baseline: 1.0596x; 1.0596x over previous
//
#include <hip/hip_runtime.h>

typedef __attribute__((ext_vector_type(8))) short short8;
typedef __attribute__((ext_vector_type(4))) float f32x4;
typedef unsigned int uint;
typedef unsigned short ushort;

#define PLF 524288   // 1024*512 elements per activation plane

__device__ __forceinline__ ushort f2bf(float f) {
  uint u = __float_as_uint(f);
  u += 0x7FFF + ((u >> 16) & 1);   // RNE
  return (ushort)(u >> 16);
}
__device__ __forceinline__ float bf2f(ushort h) {
  return __uint_as_float(((uint)h) << 16);
}
__device__ __forceinline__ int swzf(int r) { return ((r & 3) ^ ((r >> 2) & 3)); }

#define GLOAD16(gp, lp)                                          \
  __builtin_amdgcn_global_load_lds(                              \
      (const __attribute__((address_space(1))) void*)(gp),       \
      (__attribute__((address_space(3))) void*)(lp), 16, 0, 0)

// ---------------------------------------------------------------------------
// MFMA GEMM: C[m][n] = alpha * sum_k A[m][k] * B[n][k]  (both row-major-K)
// 3-buffer LDS pipeline, counted vmcnt (BCVT=0).
// MFAST=1: m-tile index fastest in block order (weight-in-B N-strip reuse).
// Per-z offsets: off = (z/Div)*S1 + (z%Mod)*S2 (element units).
// ROPE: rotary embedding in epilogue (row = position, col = feature).
// ---------------------------------------------------------------------------
template <int CDT, int BETA, int RELU2, int MFAST, int BCVT, int ROPE>
__global__ __launch_bounds__(256) void mm_kernel(
    const void* __restrict__ Av, const void* __restrict__ Bv, void* __restrict__ Cv,
    int K, int lda, int ldb, int ldc,
    int aDiv, int aMod, long long aS1, long long aS2,
    int bDiv, int bMod, long long bS1, long long bS2,
    int cDiv, int cMod, long long cS1, long long cS2, float alpha)
{
  __shared__ char lds[49152];   // 3 bufs x (A 8KB | B 8KB)
  const int nx = gridDim.x, ny = gridDim.y;
  const int nwg = nx * ny * (int)gridDim.z;
  const int o = ((int)blockIdx.z * ny + blockIdx.y) * nx + blockIdx.x;
  const int qd = nwg >> 3, rm = nwg & 7, xcd = o & 7, rot = o >> 3;
  const int wflat = (xcd < rm ? xcd * (qd + 1) : rm * (qd + 1) + (xcd - rm) * qd) + rot;
  int bx, by, bz;
  if (MFAST) { by = wflat % ny; int t2 = wflat / ny; bx = t2 % nx; bz = t2 / nx; }
  else       { bx = wflat % nx; int t2 = wflat / nx; by = t2 % ny; bz = t2 / ny; }
  const int tid = threadIdx.x;
  const long long aOff = (long long)(bz / aDiv) * aS1 + (long long)(bz % aMod) * aS2;
  const long long bOff = (long long)(bz / bDiv) * bS1 + (long long)(bz % bMod) * bS2;
  const long long cOff = (long long)(bz / cDiv) * cS1 + (long long)(bz % cMod) * cS2;
  const int m0 = by * 128, n0 = bx * 128;
  const int lane = tid & 63, wid = tid >> 6;
  const int MOFF = (wid >> 1) * 64, NOFF = (wid & 1) * 64;
  const int u = lane & 15, g = lane >> 4;
  const int sr0 = tid >> 2, sslot = tid & 3;
  const ushort* Ap = (const ushort*)Av + aOff;
  const ushort* Bp = (const ushort*)Bv + bOff;
  const float*  Bf = (const float*)Bv + bOff;

#define STAGE(buf, kt)                                                         \
  {                                                                            \
    _Pragma("unroll")                                                          \
    for (int half = 0; half < 2; ++half) {                                     \
      const int r = sr0 + 64 * half;                                           \
      const int ss = sslot ^ swzf(r);                                          \
      GLOAD16(Ap + (long long)(m0 + r) * lda + (kt) + ss * 8,                  \
              &lds[(buf) * 16384] + wid * 1024 + half * 4096);                 \
      if (BCVT == 0) {                                                         \
        GLOAD16(Bp + (long long)(n0 + r) * ldb + (kt) + ss * 8,                \
                &lds[(buf) * 16384 + 8192] + wid * 1024 + half * 4096);        \
      } else {                                                                 \
        const float* srcB = Bf + (long long)(n0 + r) * ldb + (kt) + ss * 8;    \
        float4 x0 = *(const float4*)srcB;                                      \
        float4 x1 = *(const float4*)(srcB + 4);                                \
        short8 h;                                                              \
        h[0] = (short)f2bf(x0.x); h[1] = (short)f2bf(x0.y);                    \
        h[2] = (short)f2bf(x0.z); h[3] = (short)f2bf(x0.w);                    \
        h[4] = (short)f2bf(x1.x); h[5] = (short)f2bf(x1.y);                    \
        h[6] = (short)f2bf(x1.z); h[7] = (short)f2bf(x1.w);                    \
        *(short8*)(&lds[(buf) * 16384 + 8192] + r * 64 + sslot * 16) = h;      \
      }                                                                        \
    }                                                                          \
  }

  f32x4 acc[4][4];
#pragma unroll
  for (int i = 0; i < 4; ++i)
#pragma unroll
    for (int j = 0; j < 4; ++j) acc[i][j] = (f32x4){0.f, 0.f, 0.f, 0.f};

  const int T = K >> 5;
  STAGE(0, 0);
  if (T > 1) STAGE(1, 32);
  int rb = 0, sb = 2;
  for (int t = 0; t < T; ++t) {
    if (BCVT == 0) {
      if (t + 1 < T) { asm volatile("s_waitcnt vmcnt(4)" ::: "memory"); }
      else           { asm volatile("s_waitcnt vmcnt(0)" ::: "memory"); }
    } else {
      asm volatile("s_waitcnt vmcnt(0) lgkmcnt(0)" ::: "memory");
    }
    __builtin_amdgcn_s_barrier();
    __builtin_amdgcn_sched_barrier(0);
    asm volatile("" ::: "memory");
    if (t + 2 < T) STAGE(sb, (t + 2) * 32);
    const char* Abuf = &lds[rb * 16384];
    const char* Bbuf = &lds[rb * 16384 + 8192];
    short8 af[4], bfr[4];
#pragma unroll
    for (int mi = 0; mi < 4; ++mi) {
      const int r = MOFF + mi * 16 + u;
      af[mi] = *(const short8*)(Abuf + r * 64 + ((g ^ swzf(r)) * 16));
    }
#pragma unroll
    for (int ni = 0; ni < 4; ++ni) {
      const int r = NOFF + ni * 16 + u;
      bfr[ni] = *(const short8*)(Bbuf + r * 64 + ((g ^ swzf(r)) * 16));
    }
#pragma unroll
    for (int mi = 0; mi < 4; ++mi)
#pragma unroll
      for (int ni = 0; ni < 4; ++ni)
        acc[mi][ni] = __builtin_amdgcn_mfma_f32_16x16x32_bf16(af[mi], bfr[ni], acc[mi][ni], 0, 0, 0);
    rb = (rb == 2) ? 0 : rb + 1;
    sb = (sb == 2) ? 0 : sb + 1;
  }
#undef STAGE

#pragma unroll
  for (int mi = 0; mi < 4; ++mi)
#pragma unroll
    for (int ni = 0; ni < 4; ++ni)
#pragma unroll
      for (int q = 0; q < 4; ++q) {
        const int row = m0 + MOFF + mi * 16 + g * 4 + q;
        const int col = n0 + NOFF + ni * 16 + u;
        float v = acc[mi][ni][q] * alpha;
        if (CDT == 0) {
          float* cp = (float*)Cv + cOff + (long long)row * ldc + col;
          if (BETA) v += *cp;
          *cp = v;
        } else {
          if (ROPE) {
            const int j = (col & 127) >> 1;
            const float infr = __expf((float)j * (-9.210340371976184f / 64.f));
            float sn, cs;
            __sincosf((float)row * infr, &sn, &cs);
            const float part = __shfl_xor(v, 1);
            v = (col & 1) ? fmaf(part, sn, v * cs) : fmaf(-part, sn, v * cs);
          }
          if (RELU2) { v = fmaxf(v, 0.f); v = v * v; }
          ((ushort*)Cv)[cOff + (long long)row * ldc + col] = f2bf(v);
        }
      }
}

// ---------------------------------------------------------------------------
// Fused flash attention (round-7 structure + setprio on MFMA clusters).
// ---------------------------------------------------------------------------
__global__ __launch_bounds__(256) void fattn_kernel(
    const ushort* __restrict__ Qg, const ushort* __restrict__ Kg,
    const ushort* __restrict__ Vg, ushort* __restrict__ Og)
{
  __shared__ char lds[73728];
  const int hb = blockIdx.y, pl = hb >> 3, h = hb & 7;
  const int q0 = blockIdx.x * 64;
  const int tid = threadIdx.x, lane = tid & 63, wv = tid >> 6;
  const int u = lane & 15, g = lane >> 4;
  const ushort* Qh = Qg + (size_t)pl * PLF + h * 128;
  const ushort* Kh = Kg + (size_t)pl * PLF + h * 128;
  const ushort* Vh = Vg + (size_t)pl * PLF + (size_t)(h * 128) * 512;
  ushort* Oh = Og + (size_t)pl * PLF + h * 128;

  short8 qf[4];
  const int qrow = q0 + wv * 16 + u;
#pragma unroll
  for (int dc = 0; dc < 4; ++dc)
    qf[dc] = *(const short8*)(Qh + (size_t)qrow * 1024 + dc * 32 + g * 8);

#define STAGE_KV(buf, kt)                                                     \
  {                                                                           \
    _Pragma("unroll")                                                         \
    for (int it = 0; it < 4; ++it) {                                          \
      const int off = tid * 16 + it * 4096;                                   \
      const int krow = off >> 8, kslot = (off >> 4) & 15;                     \
      GLOAD16(Kh + (size_t)((kt) * 64 + krow) * 1024 +                        \
                  ((kslot ^ ((krow & 7) << 1)) * 8),                          \
              &lds[(buf) * 16384] + off);                                     \
      const int vrow = off >> 7, vslot = (off >> 4) & 7;                      \
      GLOAD16(Vh + (size_t)vrow * 512 + (kt) * 64 + ((vslot ^ (vrow & 7)) * 8), \
              &lds[32768 + (buf) * 16384] + off);                             \
    }                                                                         \
  }

  f32x4 oacc[8];
#pragma unroll
  for (int i = 0; i < 8; ++i) oacc[i] = (f32x4){0.f, 0.f, 0.f, 0.f};
  float m_run = -3.0e38f, l_run = 0.f;

  STAGE_KV(0, 0);
  asm volatile("s_waitcnt vmcnt(0)" ::: "memory");
  __syncthreads();
  int cur = 0;
  for (int kt = 0; kt < 8; ++kt) {
    if (kt + 1 < 8) STAGE_KV(cur ^ 1, kt + 1);
    f32x4 sacc[4];
#pragma unroll
    for (int kn = 0; kn < 4; ++kn) sacc[kn] = (f32x4){0.f, 0.f, 0.f, 0.f};
    __builtin_amdgcn_s_setprio(1);
#pragma unroll
    for (int kn = 0; kn < 4; ++kn) {
      const int r = kn * 16 + u;
      const char* kb = &lds[cur * 16384] + r * 256;
#pragma unroll
      for (int dc = 0; dc < 4; ++dc) {
        short8 kf = *(const short8*)(kb + (((dc * 4 + g) ^ ((u & 7) << 1)) * 16));
        sacc[kn] = __builtin_amdgcn_mfma_f32_16x16x32_bf16(kf, qf[dc], sacc[kn], 0, 0, 0);
      }
    }
    __builtin_amdgcn_s_setprio(0);
    float pm = -3.0e38f;
#pragma unroll
    for (int kn = 0; kn < 4; ++kn)
#pragma unroll
      for (int r = 0; r < 4; ++r) {
        sacc[kn][r] *= 0.03125f;
        pm = fmaxf(pm, sacc[kn][r]);
      }
    pm = fmaxf(pm, __shfl_xor(pm, 16));
    pm = fmaxf(pm, __shfl_xor(pm, 32));
    const float m_new = fmaxf(m_run, pm);
    const float es = __expf(m_run - m_new);
    float psum = 0.f;
    uint pw[4][2];
#pragma unroll
    for (int kn = 0; kn < 4; ++kn) {
      float p0 = __expf(sacc[kn][0] - m_new);
      float p1 = __expf(sacc[kn][1] - m_new);
      float p2 = __expf(sacc[kn][2] - m_new);
      float p3 = __expf(sacc[kn][3] - m_new);
      psum += (p0 + p1) + (p2 + p3);
      pw[kn][0] = (uint)f2bf(p0) | ((uint)f2bf(p1) << 16);
      pw[kn][1] = (uint)f2bf(p2) | ((uint)f2bf(p3) << 16);
    }
    psum += __shfl_xor(psum, 16);
    psum += __shfl_xor(psum, 32);
    l_run = l_run * es + psum;
    m_run = m_new;
    char* pb = &lds[65536 + wv * 2048] + u * 128 + (g & 1) * 8;
#pragma unroll
    for (int kn = 0; kn < 4; ++kn)
      *(uint2*)(pb + (((2 * kn + (g >> 1)) ^ (u & 7)) * 16)) =
          make_uint2(pw[kn][0], pw[kn][1]);
    float es_o[4];
#pragma unroll
    for (int r = 0; r < 4; ++r) es_o[r] = __shfl(es, g * 4 + r);
#pragma unroll
    for (int nd = 0; nd < 8; ++nd)
#pragma unroll
      for (int r = 0; r < 4; ++r) oacc[nd][r] *= es_o[r];
    const char* prd = &lds[65536 + wv * 2048] + u * 128;
    short8 pf[2];
#pragma unroll
    for (int kc = 0; kc < 2; ++kc)
      pf[kc] = *(const short8*)(prd + (((kc * 4 + g) ^ (u & 7)) * 16));
    __builtin_amdgcn_s_setprio(1);
#pragma unroll
    for (int nd = 0; nd < 8; ++nd) {
      const int vr = nd * 16 + u;
      const char* vb = &lds[32768 + cur * 16384] + vr * 128;
#pragma unroll
      for (int kc = 0; kc < 2; ++kc) {
        short8 vf = *(const short8*)(vb + (((kc * 4 + g) ^ (u & 7)) * 16));
        oacc[nd] = __builtin_amdgcn_mfma_f32_16x16x32_bf16(pf[kc], vf, oacc[nd], 0, 0, 0);
      }
    }
    __builtin_amdgcn_s_setprio(0);
    asm volatile("s_waitcnt vmcnt(0)" ::: "memory");
    __syncthreads();
    cur ^= 1;
  }
#undef STAGE_KV
  const float inv_l = 1.f / l_run;
  float inv_o[4];
#pragma unroll
  for (int r = 0; r < 4; ++r) inv_o[r] = __shfl(inv_l, g * 4 + r);
#pragma unroll
  for (int nd = 0; nd < 8; ++nd)
#pragma unroll
    for (int r = 0; r < 4; ++r) {
      const int row = q0 + wv * 16 + g * 4 + r;
      Oh[(size_t)row * 1024 + nd * 16 + u] = f2bf(oacc[nd][r] * inv_o[r]);
    }
}

// ---------------- fp32 -> bf16 weight conversion (8 elem/thread) ------------
__global__ __launch_bounds__(256) void cvt_kernel(
    const float4* __restrict__ s, short8* __restrict__ d)
{
  const int i = blockIdx.x * 256 + threadIdx.x;
  const float4 a = s[2 * i], b = s[2 * i + 1];
  short8 h;
  h[0] = (short)f2bf(a.x); h[1] = (short)f2bf(a.y);
  h[2] = (short)f2bf(a.z); h[3] = (short)f2bf(a.w);
  h[4] = (short)f2bf(b.x); h[5] = (short)f2bf(b.y);
  h[6] = (short)f2bf(b.z); h[7] = (short)f2bf(b.w);
  d[i] = h;
}

// ---------------------------------------------------------------------------
// conv 3x3 SAME on [512 w][F f] planes; 2 w-rows x 8 f x 4 co per thread.
// Rows w-1..w+2 loaded once, shared by both outputs.
// ---------------------------------------------------------------------------
template <int CIN>
__global__ __launch_bounds__(256) void conv4c_kernel(
    const ushort* __restrict__ in, const float* __restrict__ wt,
    const float* __restrict__ bias, ushort* __restrict__ outp, int log2F)
{
  const int idx = blockIdx.x * 256 + threadIdx.x;
  const int F8m = (1 << (log2F - 3)) - 1;
  const int f8 = idx & F8m;
  const int wp2 = (idx >> (log2F - 3)) & 255;
  const int bb = idx >> (log2F + 5);
  const int w = wp2 * 2;
  const int f0 = f8 << 3;
  float acc[2][4][8];
#pragma unroll
  for (int co = 0; co < 4; ++co) {
    const float bv = bias[co];
#pragma unroll
    for (int j = 0; j < 8; ++j) { acc[0][co][j] = bv; acc[1][co][j] = bv; }
  }
  const bool lok = f8 > 0, rok = f8 < F8m;
#pragma unroll
  for (int ci = 0; ci < CIN; ++ci) {
    const ushort* base = in + (((size_t)(bb * CIN + ci)) << (log2F + 9));
#pragma unroll
    for (int rr = 0; rr < 4; ++rr) {
      const int wr = w - 1 + rr;
      if (wr < 0 || wr > 511) continue;
      const ushort* rp = base + ((size_t)wr << log2F) + f0;
      const short8 cen = *(const short8*)rp;
      float xv[10];
      xv[0] = lok ? bf2f(rp[-1]) : 0.f;
#pragma unroll
      for (int j = 0; j < 8; ++j) xv[j + 1] = bf2f((ushort)cen[j]);
      xv[9] = rok ? bf2f(rp[8]) : 0.f;
#pragma unroll
      for (int co = 0; co < 4; ++co) {
        const float* wp = wt + (co * CIN + ci) * 9;
        if (rr <= 2) {
          const float k0 = wp[rr], k1 = wp[3 + rr], k2 = wp[6 + rr];
#pragma unroll
          for (int j = 0; j < 8; ++j)
            acc[0][co][j] += k0 * xv[j] + k1 * xv[j + 1] + k2 * xv[j + 2];
        }
        if (rr >= 1) {
          const float k0 = wp[rr - 1], k1 = wp[2 + rr], k2 = wp[5 + rr];
#pragma unroll
          for (int j = 0; j < 8; ++j)
            acc[1][co][j] += k0 * xv[j] + k1 * xv[j + 1] + k2 * xv[j + 2];
        }
      }
    }
  }
#pragma unroll
  for (int wo = 0; wo < 2; ++wo)
#pragma unroll
    for (int co = 0; co < 4; ++co) {
      short8 o;
#pragma unroll
      for (int j = 0; j < 8; ++j) o[j] = (short)f2bf(acc[wo][co][j]);
      *(short8*)(outp + (((size_t)(bb * 4 + co)) << (log2F + 9)) +
                 ((size_t)(w + wo) << log2F) + f0) = o;
    }
}

// ---------------------------------------------------------------------------
// q/k/v merged conv: reads XN once, computes 12 output channels (3 proj x 4c).
// ---------------------------------------------------------------------------
__global__ __launch_bounds__(256) void conv12c_kernel(
    const ushort* __restrict__ in,
    const float* __restrict__ wq, const float* __restrict__ wk, const float* __restrict__ wv,
    const float* __restrict__ bq, const float* __restrict__ bk, const float* __restrict__ bv,
    ushort* __restrict__ outp, int nPl)
{
  const int idx = blockIdx.x * 256 + threadIdx.x;
  const int f8 = idx & 127;
  const int w = (idx >> 7) & 511;
  const int bb = idx >> 16;
  const int f0 = f8 << 3;
  const float* wsel[3] = {wq, wk, wv};
  float acc[12][8];
#pragma unroll
  for (int co = 0; co < 4; ++co) {
    const float b0 = bq[co], b1 = bk[co], b2 = bv[co];
#pragma unroll
    for (int j = 0; j < 8; ++j) {
      acc[co][j] = b0; acc[4 + co][j] = b1; acc[8 + co][j] = b2;
    }
  }
  const bool lok = f8 > 0, rok = f8 < 127;
#pragma unroll
  for (int ci = 0; ci < 4; ++ci) {
    const ushort* base = in + (((size_t)(bb * 4 + ci)) << 19);
#pragma unroll
    for (int dxw = 0; dxw < 3; ++dxw) {
      const int w2 = w + dxw - 1;
      if (w2 < 0 || w2 > 511) continue;
      const ushort* rp = base + ((size_t)w2 << 10) + f0;
      const short8 cen = *(const short8*)rp;
      float xv[10];
      xv[0] = lok ? bf2f(rp[-1]) : 0.f;
#pragma unroll
      for (int j = 0; j < 8; ++j) xv[j + 1] = bf2f((ushort)cen[j]);
      xv[9] = rok ? bf2f(rp[8]) : 0.f;
#pragma unroll
      for (int pj = 0; pj < 3; ++pj)
#pragma unroll
        for (int co = 0; co < 4; ++co) {
          const float* wp = wsel[pj] + (co * 4 + ci) * 9;
          const float k0 = wp[dxw], k1 = wp[3 + dxw], k2 = wp[6 + dxw];
#pragma unroll
          for (int j = 0; j < 8; ++j)
            acc[pj * 4 + co][j] += k0 * xv[j] + k1 * xv[j + 1] + k2 * xv[j + 2];
        }
    }
  }
#pragma unroll
  for (int pj = 0; pj < 3; ++pj)
#pragma unroll
    for (int co = 0; co < 4; ++co) {
      short8 o;
#pragma unroll
      for (int j = 0; j < 8; ++j) o[j] = (short)f2bf(acc[pj * 4 + co][j]);
      *(short8*)(outp + (((size_t)(pj * nPl + bb * 4 + co)) << 19) +
                 ((size_t)w << 10) + f0) = o;
    }
}

// ---------------- layernorm over f (rows of 1024), H fp32 -> XN bf16 --------
__global__ __launch_bounds__(256) void ln_kernel(
    const float* __restrict__ H, const float* __restrict__ gam,
    const float* __restrict__ bet, ushort* __restrict__ XN)
{
  const int wid = threadIdx.x >> 6, lane = threadIdx.x & 63;
  const int row = blockIdx.x * 4 + wid;
  const int c = (row >> 9) & 3;
  const float* xp = H + (size_t)row * 1024;
  float4 v[4];
  float s = 0.f, q = 0.f;
#pragma unroll
  for (int p = 0; p < 4; ++p) {
    v[p] = *(const float4*)(xp + p * 256 + lane * 4);
    s += v[p].x + v[p].y + v[p].z + v[p].w;
    q += v[p].x * v[p].x + v[p].y * v[p].y + v[p].z * v[p].z + v[p].w * v[p].w;
  }
#pragma unroll
  for (int o = 32; o > 0; o >>= 1) { s += __shfl_xor(s, o); q += __shfl_xor(q, o); }
  const float mu = s * (1.f / 1024.f);
  const float var = q * (1.f / 1024.f) - mu * mu;
  const float rs = rsqrtf(var + 1e-5f);
  ushort* op = XN + (size_t)row * 1024;
  const float* gp = gam + c * 1024;
  const float* bp = bet + c * 1024;
#pragma unroll
  for (int p = 0; p < 4; ++p) {
    const int f = p * 256 + lane * 4;
    float4 g4 = *(const float4*)(gp + f);
    float4 b4 = *(const float4*)(bp + f);
    ushort4 o4;
    o4.x = f2bf((v[p].x - mu) * rs * g4.x + b4.x);
    o4.y = f2bf((v[p].y - mu) * rs * g4.y + b4.y);
    o4.z = f2bf((v[p].z - mu) * rs * g4.z + b4.z);
    o4.w = f2bf((v[p].w - mu) * rs * g4.w + b4.w);
    *(ushort4*)(op + f) = o4;
  }
}

// ---- transpose-in: x fp32 [f][w] -> XT bf16 [w][f]; also copy x -> out -----
__global__ __launch_bounds__(256) void tin_kernel(
    const float* __restrict__ x, ushort* __restrict__ XT,
    float* __restrict__ outp, int planeOff)
{
  __shared__ float t[32][33];
  const int f0 = blockIdx.x * 32, w0 = blockIdx.y * 32;
  const int z = blockIdx.z;
  const int tx = threadIdx.x & 31, ty = threadIdx.x >> 5;
  const int gpl = planeOff + z;
  const int b = gpl >> 3, ch = gpl & 7;
  const float* src = x + (size_t)gpl * PLF;
  float* dst0 = outp + (size_t)(b * 12 + ch) * PLF;
#pragma unroll
  for (int r = 0; r < 32; r += 8) {
    const size_t off = (size_t)(f0 + r + ty) * 512 + w0 + tx;
    const float v = src[off];
    t[r + ty][tx] = v;
    dst0[off] = v;
  }
  __syncthreads();
  ushort* dst = XT + (size_t)z * PLF;
#pragma unroll
  for (int r = 0; r < 32; r += 8) dst[(size_t)(w0 + r + ty) * 1024 + f0 + tx] = f2bf(t[tx][r + ty]);
}

// ---------------- transpose-out: H fp32 [w][f] -> out[b][8+c][f][w] ---------
__global__ __launch_bounds__(256) void tout_kernel(
    const float* __restrict__ H, float* __restrict__ out, int b0)
{
  __shared__ float t[32][33];
  const int w0 = blockIdx.x * 32, f0 = blockIdx.y * 32;
  const int p = blockIdx.z;
  const int b = b0 + (p >> 2), c = p & 3;
  const int tx = threadIdx.x & 31, ty = threadIdx.x >> 5;
  const float* src = H + (size_t)p * PLF;
#pragma unroll
  for (int r = 0; r < 32; r += 8) t[r + ty][tx] = src[(size_t)(w0 + r + ty) * 1024 + f0 + tx];
  __syncthreads();
  float* dst = out + (size_t)(b * 12 + 8 + c) * PLF;
#pragma unroll
  for (int r = 0; r < 32; r += 8) dst[(size_t)(f0 + r + ty) * 512 + w0 + tx] = t[tx][r + ty];
}

// ---------------------------------------------------------------------------
extern "C" void kernel_launch(void* const* d_in, const int* in_sizes, int n_in,
                              void* d_out, int out_size, void* d_ws, size_t ws_size,
                              hipStream_t stream)
{
  const float* x        = (const float*)d_in[0];
  const float* embed_cw = (const float*)d_in[1];
  const float* embed_cb = (const float*)d_in[2];
  const float* embed_pw = (const float*)d_in[3];
  const float* n1g      = (const float*)d_in[4];
  const float* n1b      = (const float*)d_in[5];
  const float* q_cw     = (const float*)d_in[6];
  const float* q_cb     = (const float*)d_in[7];
  const float* q_pw     = (const float*)d_in[8];
  const float* k_cw     = (const float*)d_in[9];
  const float* k_cb     = (const float*)d_in[10];
  const float* k_pw     = (const float*)d_in[11];
  const float* v_cw     = (const float*)d_in[12];
  const float* v_cb     = (const float*)d_in[13];
  const float* v_pw     = (const float*)d_in[14];
  const float* o_cw     = (const float*)d_in[15];
  const float* o_cb     = (const float*)d_in[16];
  const float* o_pw     = (const float*)d_in[17];
  const float* n2g      = (const float*)d_in[18];
  const float* n2b      = (const float*)d_in[19];
  const float* f1_cw    = (const float*)d_in[20];
  const float* f1_cb    = (const float*)d_in[21];
  const float* f1_pw    = (const float*)d_in[22];
  const float* f2_cw    = (const float*)d_in[23];
  const float* f2_cb    = (const float*)d_in[24];
  const float* f2_pw    = (const float*)d_in[25];
  float* out = (float*)d_out;

  const size_t perB = 50331648ull;
  const int N = (ws_size >= 4 * perB) ? 4 : (ws_size >= 2 * perB) ? 2 : 1;
  const int nP = 4 * N;

  // layout: Hf | XT | XN | Qb | Kb | CT | Vb | SfPb
  char* base = (char*)d_ws;
  float*  Hf = (float*)base;                                    // N*8388608 B
  ushort* XT = (ushort*)(base + (size_t)N * 8388608);           // N*8388608 B
  ushort* XN = (ushort*)((char*)XT + (size_t)N * 8388608);      // N*4194304 B
  ushort* Qb = (ushort*)((char*)XN + (size_t)N * 4194304);
  ushort* Kb = (ushort*)((char*)Qb + (size_t)N * 4194304);      // adjacent to Qb!
  ushort* CT = (ushort*)((char*)Kb + (size_t)N * 4194304);
  ushort* Vb = (ushort*)((char*)CT + (size_t)N * 4194304);
  ushort* SfPb = (ushort*)((char*)Vb + (size_t)N * 4194304);    // N*12582912 B
  ushort* CT3 = SfPb;                  // q/k/v conv outputs, 3*nP planes
  ushort* W8  = SfPb;                  // 8.4MB bf16 weight slot (embed/o/v)
  ushort* WQK = XT;                    // 16.8MB qk weights (N>=2)
  ushort* MID = XT;                    // ffn1 out (XT..Qb span)
  ushort* f1w = Vb;                    // ffn1 weight (Vb..SfPb span, N>=2)
  ushort* F2C = Vb;                    // ffn2 conv out (Vb..SfPb span)
  ushort* f2w = XT;                    // ffn2 weight (XT..Qb span, N>=2)

  const long long W1 = 1048576;
  const long long W4 = 4194304;
  const long long M1 = 2097152;
  const long long CH3 = (long long)nP * PLF;   // CT3 chunk stride
  const int GCc1 = N * 128;            // 2-row conv blocks at F=1024
  const int GCc4 = N * 512;            // 2-row conv blocks at F=4096
  const int GC12 = N * 256;

  for (int b0 = 0; b0 < 4; b0 += N) {
    // --- input transpose + x copy to out ---
    tin_kernel<<<dim3(32, 16, 8 * N), 256, 0, stream>>>(x, XT, out, b0 * 8);
    // --- embed ---
    conv4c_kernel<8><<<GCc1, 256, 0, stream>>>(XT, embed_cw, embed_cb, CT, 10);
    cvt_kernel<<<2048, 256, 0, stream>>>((const float4*)embed_pw, (short8*)W8);
    mm_kernel<0, 0, 0, 1, 0, 0><<<dim3(8, 4, nP), 256, 0, stream>>>(
        CT, W8, Hf, 1024, 1024, 1024, 1024,
        1, 1, PLF, 0, 4, 4, 0, W1, 1, 1, PLF, 0, 1.f);
    // --- LN1 ---
    ln_kernel<<<nP * 128, 256, 0, stream>>>(Hf, n1g, n1b, XN);
    // --- merged q/k/v conv ---
    conv12c_kernel<<<GC12, 256, 0, stream>>>(XN, q_cw, k_cw, v_cw,
                                             q_cb, k_cb, v_cb, CT3, nP);
    // --- q+k projection (RoPE fused into epilogue) ---
    if (N >= 2) {
      cvt_kernel<<<2048, 256, 0, stream>>>((const float4*)q_pw, (short8*)WQK);
      cvt_kernel<<<2048, 256, 0, stream>>>((const float4*)k_pw, (short8*)(WQK) + 524288);
      mm_kernel<1, 0, 0, 1, 0, 1><<<dim3(8, 4, 2 * nP), 256, 0, stream>>>(
          CT3, WQK, Qb, 1024, 1024, 1024, 1024,
          1, 1, PLF, 0, nP, 4, 4 * W1, W1, 1, 1, PLF, 0, 1.f);
    } else {
      mm_kernel<1, 0, 0, 1, 1, 1><<<dim3(8, 4, nP), 256, 0, stream>>>(
          CT3, q_pw, Qb, 1024, 1024, 1024, 1024,
          1, 1, PLF, 0, 4, 4, 0, W1, 1, 1, PLF, 0, 1.f);
      mm_kernel<1, 0, 0, 1, 1, 1><<<dim3(8, 4, nP), 256, 0, stream>>>(
          CT3 + CH3, k_pw, Kb, 1024, 1024, 1024, 1024,
          1, 1, PLF, 0, 4, 4, 0, W1, 1, 1, PLF, 0, 1.f);
    }
    // --- v projection (V stored [f][w]); W8 clobbers CT3 chunk0 (dead) ---
    cvt_kernel<<<2048, 256, 0, stream>>>((const float4*)v_pw, (short8*)W8);
    mm_kernel<1, 0, 0, 0, 0, 0><<<dim3(4, 8, nP), 256, 0, stream>>>(
        W8, CT3 + 2 * CH3, Vb, 1024, 1024, 1024, 512,
        4, 4, 0, W1, 1, 1, PLF, 0, 1, 1, PLF, 0, 1.f);
    // --- fused flash attention (O overwrites Q) ---
    fattn_kernel<<<dim3(8, nP * 8), 256, 0, stream>>>(Qb, Kb, Vb, Qb);
    // --- o projection (accumulate into H) ---
    conv4c_kernel<4><<<GCc1, 256, 0, stream>>>(Qb, o_cw, o_cb, CT, 10);
    cvt_kernel<<<2048, 256, 0, stream>>>((const float4*)o_pw, (short8*)W8);
    mm_kernel<0, 1, 0, 1, 0, 0><<<dim3(8, 4, nP), 256, 0, stream>>>(
        CT, W8, Hf, 1024, 1024, 1024, 1024,
        1, 1, PLF, 0, 4, 4, 0, W1, 1, 1, PLF, 0, 1.f);
    // --- LN2 ---
    ln_kernel<<<nP * 128, 256, 0, stream>>>(Hf, n2g, n2b, XN);
    // --- ffn1 (+fused squared relu) ---
    conv4c_kernel<4><<<GCc1, 256, 0, stream>>>(XN, f1_cw, f1_cb, CT, 10);
    if (N >= 2) {
      cvt_kernel<<<8192, 256, 0, stream>>>((const float4*)f1_pw, (short8*)f1w);
      mm_kernel<1, 0, 1, 1, 0, 0><<<dim3(32, 4, nP), 256, 0, stream>>>(
          CT, f1w, MID, 1024, 1024, 1024, 4096,
          1, 1, PLF, 0, 4, 4, 0, W4, 1, 1, M1, 0, 1.f);
    } else {
      mm_kernel<1, 0, 1, 1, 1, 0><<<dim3(32, 4, nP), 256, 0, stream>>>(
          CT, f1_pw, MID, 1024, 1024, 1024, 4096,
          1, 1, PLF, 0, 4, 4, 0, W4, 1, 1, M1, 0, 1.f);
    }
    // --- ffn2 conv (F=4096) then pw accumulate into H ---
    conv4c_kernel<4><<<GCc4, 256, 0, stream>>>(MID, f2_cw, f2_cb, F2C, 12);
    if (N >= 2) {
      cvt_kernel<<<8192, 256, 0, stream>>>((const float4*)f2_pw, (short8*)f2w);
      mm_kernel<0, 1, 0, 1, 0, 0><<<dim3(8, 4, nP), 256, 0, stream>>>(
          F2C, f2w, Hf, 4096, 4096, 4096, 1024,
          1, 1, M1, 0, 4, 4, 0, W4, 1, 1, PLF, 0, 1.f);
    } else {
      mm_kernel<0, 1, 0, 1, 1, 0><<<dim3(8, 4, nP), 256, 0, stream>>>(
          F2C, f2_pw, Hf, 4096, 4096, 4096, 1024,
          1, 1, M1, 0, 4, 4, 0, W4, 1, 1, PLF, 0, 1.f);
    }
    // --- output transpose ---
    tout_kernel<<<dim3(16, 32, nP), 256, 0, stream>>>(Hf, out, b0);
  }
}

// Round 12
// 646.882 us; speedup vs baseline: 1.0806x; 1.0198x over previous
//
#include <hip/hip_runtime.h>

typedef __attribute__((ext_vector_type(8))) short short8;
typedef __attribute__((ext_vector_type(4))) float f32x4;
typedef unsigned int uint;
typedef unsigned short ushort;

#define PLF 524288   // 1024*512 elements per activation plane

__device__ __forceinline__ ushort f2bf(float f) {
  uint u = __float_as_uint(f);
  u += 0x7FFF + ((u >> 16) & 1);   // RNE
  return (ushort)(u >> 16);
}
__device__ __forceinline__ float bf2f(ushort h) {
  return __uint_as_float(((uint)h) << 16);
}
__device__ __forceinline__ int swzf(int r) { return ((r & 3) ^ ((r >> 2) & 3)); }

#define GLOAD16(gp, lp)                                          \
  __builtin_amdgcn_global_load_lds(                              \
      (const __attribute__((address_space(1))) void*)(gp),       \
      (__attribute__((address_space(3))) void*)(lp), 16, 0, 0)

// ---------------------------------------------------------------------------
// mm2: 8-wave 128(M)x256(N) MFMA GEMM, bf16 A/B (global_load_lds), BK=32.
// 3-buffer LDS pipeline (24KB/buf), counted vmcnt(3), one barrier per K-step.
// Waves: 2(M)x4(N), each 64x64 output (4x4 frags). Same swizzle as mm_kernel.
// ---------------------------------------------------------------------------
template <int CDT, int BETA, int RELU2, int MFAST, int ROPE>
__global__ __launch_bounds__(512) void mm2_kernel(
    const ushort* __restrict__ Av, const ushort* __restrict__ Bv, void* __restrict__ Cv,
    int K, int lda, int ldb, int ldc,
    int aDiv, int aMod, long long aS1, long long aS2,
    int bDiv, int bMod, long long bS1, long long bS2,
    int cDiv, int cMod, long long cS1, long long cS2, float alpha)
{
  __shared__ char lds[73728];   // 3 bufs x (A 8KB | B 16KB)
  const int nx = gridDim.x, ny = gridDim.y;
  const int nwg = nx * ny * (int)gridDim.z;
  const int o = ((int)blockIdx.z * ny + blockIdx.y) * nx + blockIdx.x;
  const int qd = nwg >> 3, rm = nwg & 7, xcd = o & 7, rot = o >> 3;
  const int wflat = (xcd < rm ? xcd * (qd + 1) : rm * (qd + 1) + (xcd - rm) * qd) + rot;
  int bx, by, bz;
  if (MFAST) { by = wflat % ny; int t2 = wflat / ny; bx = t2 % nx; bz = t2 / nx; }
  else       { bx = wflat % nx; int t2 = wflat / nx; by = t2 % ny; bz = t2 / ny; }
  const int tid = threadIdx.x;
  const long long aOff = (long long)(bz / aDiv) * aS1 + (long long)(bz % aMod) * aS2;
  const long long bOff = (long long)(bz / bDiv) * bS1 + (long long)(bz % bMod) * bS2;
  const long long cOff = (long long)(bz / cDiv) * cS1 + (long long)(bz % cMod) * cS2;
  const int m0 = by * 128, n0 = bx * 256;
  const int lane = tid & 63, wid = tid >> 6;            // 8 waves
  const int MOFF = (wid >> 2) * 64, NOFF = (wid & 3) * 64;
  const int u = lane & 15, g = lane >> 4;
  const int sr0 = tid >> 2, sslot = tid & 3;            // sr0: 0..127
  const ushort* Ap = Av + aOff;
  const ushort* Bp = Bv + bOff;

#define STAGE2(buf, kt)                                                        \
  {                                                                            \
    {                                                                          \
      const int r = sr0;                                                       \
      const int ss = sslot ^ swzf(r);                                          \
      GLOAD16(Ap + (long long)(m0 + r) * lda + (kt) + ss * 8,                  \
              &lds[(buf) * 24576] + tid * 16);                                 \
    }                                                                          \
    _Pragma("unroll")                                                          \
    for (int half = 0; half < 2; ++half) {                                     \
      const int r = sr0 + 128 * half;                                          \
      const int ss = sslot ^ swzf(r);                                          \
      GLOAD16(Bp + (long long)(n0 + r) * ldb + (kt) + ss * 8,                  \
              &lds[(buf) * 24576 + 8192] + half * 8192 + tid * 16);            \
    }                                                                          \
  }

  f32x4 acc[4][4];
#pragma unroll
  for (int i = 0; i < 4; ++i)
#pragma unroll
    for (int j = 0; j < 4; ++j) acc[i][j] = (f32x4){0.f, 0.f, 0.f, 0.f};

  const int T = K >> 5;
  STAGE2(0, 0);
  if (T > 1) STAGE2(1, 32);
  int rb = 0, sb = 2;
  for (int t = 0; t < T; ++t) {
    if (t + 1 < T) { asm volatile("s_waitcnt vmcnt(3)" ::: "memory"); }
    else           { asm volatile("s_waitcnt vmcnt(0)" ::: "memory"); }
    __builtin_amdgcn_s_barrier();
    __builtin_amdgcn_sched_barrier(0);
    asm volatile("" ::: "memory");
    if (t + 2 < T) STAGE2(sb, (t + 2) * 32);
    const char* Abuf = &lds[rb * 24576];
    const char* Bbuf = &lds[rb * 24576 + 8192];
    short8 af[4], bfr[4];
#pragma unroll
    for (int mi = 0; mi < 4; ++mi) {
      const int r = MOFF + mi * 16 + u;
      af[mi] = *(const short8*)(Abuf + r * 64 + ((g ^ swzf(r)) * 16));
    }
#pragma unroll
    for (int ni = 0; ni < 4; ++ni) {
      const int r = NOFF + ni * 16 + u;
      bfr[ni] = *(const short8*)(Bbuf + r * 64 + ((g ^ swzf(r)) * 16));
    }
    __builtin_amdgcn_s_setprio(1);
#pragma unroll
    for (int mi = 0; mi < 4; ++mi)
#pragma unroll
      for (int ni = 0; ni < 4; ++ni)
        acc[mi][ni] = __builtin_amdgcn_mfma_f32_16x16x32_bf16(af[mi], bfr[ni], acc[mi][ni], 0, 0, 0);
    __builtin_amdgcn_s_setprio(0);
    rb = (rb == 2) ? 0 : rb + 1;
    sb = (sb == 2) ? 0 : sb + 1;
  }
#undef STAGE2

#pragma unroll
  for (int mi = 0; mi < 4; ++mi)
#pragma unroll
    for (int ni = 0; ni < 4; ++ni)
#pragma unroll
      for (int q = 0; q < 4; ++q) {
        const int row = m0 + MOFF + mi * 16 + g * 4 + q;
        const int col = n0 + NOFF + ni * 16 + u;
        float v = acc[mi][ni][q] * alpha;
        if (CDT == 0) {
          float* cp = (float*)Cv + cOff + (long long)row * ldc + col;
          if (BETA) v += *cp;
          *cp = v;
        } else {
          if (ROPE) {
            const int j = (col & 127) >> 1;
            const float infr = __expf((float)j * (-9.210340371976184f / 64.f));
            float sn, cs;
            __sincosf((float)row * infr, &sn, &cs);
            const float part = __shfl_xor(v, 1);
            v = (col & 1) ? fmaf(part, sn, v * cs) : fmaf(-part, sn, v * cs);
          }
          if (RELU2) { v = fmaxf(v, 0.f); v = v * v; }
          ((ushort*)Cv)[cOff + (long long)row * ldc + col] = f2bf(v);
        }
      }
}

// ---------------------------------------------------------------------------
// Legacy 4-wave 128x128 GEMM (kept for N==1 fp32-weight fallback paths).
// ---------------------------------------------------------------------------
template <int CDT, int BETA, int RELU2, int MFAST, int BCVT, int ROPE>
__global__ __launch_bounds__(256) void mm_kernel(
    const void* __restrict__ Av, const void* __restrict__ Bv, void* __restrict__ Cv,
    int K, int lda, int ldb, int ldc,
    int aDiv, int aMod, long long aS1, long long aS2,
    int bDiv, int bMod, long long bS1, long long bS2,
    int cDiv, int cMod, long long cS1, long long cS2, float alpha)
{
  __shared__ char lds[49152];
  const int nx = gridDim.x, ny = gridDim.y;
  const int nwg = nx * ny * (int)gridDim.z;
  const int o = ((int)blockIdx.z * ny + blockIdx.y) * nx + blockIdx.x;
  const int qd = nwg >> 3, rm = nwg & 7, xcd = o & 7, rot = o >> 3;
  const int wflat = (xcd < rm ? xcd * (qd + 1) : rm * (qd + 1) + (xcd - rm) * qd) + rot;
  int bx, by, bz;
  if (MFAST) { by = wflat % ny; int t2 = wflat / ny; bx = t2 % nx; bz = t2 / nx; }
  else       { bx = wflat % nx; int t2 = wflat / nx; by = t2 % ny; bz = t2 / ny; }
  const int tid = threadIdx.x;
  const long long aOff = (long long)(bz / aDiv) * aS1 + (long long)(bz % aMod) * aS2;
  const long long bOff = (long long)(bz / bDiv) * bS1 + (long long)(bz % bMod) * bS2;
  const long long cOff = (long long)(bz / cDiv) * cS1 + (long long)(bz % cMod) * cS2;
  const int m0 = by * 128, n0 = bx * 128;
  const int lane = tid & 63, wid = tid >> 6;
  const int MOFF = (wid >> 1) * 64, NOFF = (wid & 1) * 64;
  const int u = lane & 15, g = lane >> 4;
  const int sr0 = tid >> 2, sslot = tid & 3;
  const ushort* Ap = (const ushort*)Av + aOff;
  const ushort* Bp = (const ushort*)Bv + bOff;
  const float*  Bf = (const float*)Bv + bOff;

#define STAGE(buf, kt)                                                         \
  {                                                                            \
    _Pragma("unroll")                                                          \
    for (int half = 0; half < 2; ++half) {                                     \
      const int r = sr0 + 64 * half;                                           \
      const int ss = sslot ^ swzf(r);                                          \
      GLOAD16(Ap + (long long)(m0 + r) * lda + (kt) + ss * 8,                  \
              &lds[(buf) * 16384] + wid * 1024 + half * 4096);                 \
      if (BCVT == 0) {                                                         \
        GLOAD16(Bp + (long long)(n0 + r) * ldb + (kt) + ss * 8,                \
                &lds[(buf) * 16384 + 8192] + wid * 1024 + half * 4096);        \
      } else {                                                                 \
        const float* srcB = Bf + (long long)(n0 + r) * ldb + (kt) + ss * 8;    \
        float4 x0 = *(const float4*)srcB;                                      \
        float4 x1 = *(const float4*)(srcB + 4);                                \
        short8 h;                                                              \
        h[0] = (short)f2bf(x0.x); h[1] = (short)f2bf(x0.y);                    \
        h[2] = (short)f2bf(x0.z); h[3] = (short)f2bf(x0.w);                    \
        h[4] = (short)f2bf(x1.x); h[5] = (short)f2bf(x1.y);                    \
        h[6] = (short)f2bf(x1.z); h[7] = (short)f2bf(x1.w);                    \
        *(short8*)(&lds[(buf) * 16384 + 8192] + r * 64 + sslot * 16) = h;      \
      }                                                                        \
    }                                                                          \
  }

  f32x4 acc[4][4];
#pragma unroll
  for (int i = 0; i < 4; ++i)
#pragma unroll
    for (int j = 0; j < 4; ++j) acc[i][j] = (f32x4){0.f, 0.f, 0.f, 0.f};

  const int T = K >> 5;
  STAGE(0, 0);
  if (T > 1) STAGE(1, 32);
  int rb = 0, sb = 2;
  for (int t = 0; t < T; ++t) {
    if (BCVT == 0) {
      if (t + 1 < T) { asm volatile("s_waitcnt vmcnt(4)" ::: "memory"); }
      else           { asm volatile("s_waitcnt vmcnt(0)" ::: "memory"); }
    } else {
      asm volatile("s_waitcnt vmcnt(0) lgkmcnt(0)" ::: "memory");
    }
    __builtin_amdgcn_s_barrier();
    __builtin_amdgcn_sched_barrier(0);
    asm volatile("" ::: "memory");
    if (t + 2 < T) STAGE(sb, (t + 2) * 32);
    const char* Abuf = &lds[rb * 16384];
    const char* Bbuf = &lds[rb * 16384 + 8192];
    short8 af[4], bfr[4];
#pragma unroll
    for (int mi = 0; mi < 4; ++mi) {
      const int r = MOFF + mi * 16 + u;
      af[mi] = *(const short8*)(Abuf + r * 64 + ((g ^ swzf(r)) * 16));
    }
#pragma unroll
    for (int ni = 0; ni < 4; ++ni) {
      const int r = NOFF + ni * 16 + u;
      bfr[ni] = *(const short8*)(Bbuf + r * 64 + ((g ^ swzf(r)) * 16));
    }
#pragma unroll
    for (int mi = 0; mi < 4; ++mi)
#pragma unroll
      for (int ni = 0; ni < 4; ++ni)
        acc[mi][ni] = __builtin_amdgcn_mfma_f32_16x16x32_bf16(af[mi], bfr[ni], acc[mi][ni], 0, 0, 0);
    rb = (rb == 2) ? 0 : rb + 1;
    sb = (sb == 2) ? 0 : sb + 1;
  }
#undef STAGE

#pragma unroll
  for (int mi = 0; mi < 4; ++mi)
#pragma unroll
    for (int ni = 0; ni < 4; ++ni)
#pragma unroll
      for (int q = 0; q < 4; ++q) {
        const int row = m0 + MOFF + mi * 16 + g * 4 + q;
        const int col = n0 + NOFF + ni * 16 + u;
        float v = acc[mi][ni][q] * alpha;
        if (CDT == 0) {
          float* cp = (float*)Cv + cOff + (long long)row * ldc + col;
          if (BETA) v += *cp;
          *cp = v;
        } else {
          if (ROPE) {
            const int j = (col & 127) >> 1;
            const float infr = __expf((float)j * (-9.210340371976184f / 64.f));
            float sn, cs;
            __sincosf((float)row * infr, &sn, &cs);
            const float part = __shfl_xor(v, 1);
            v = (col & 1) ? fmaf(part, sn, v * cs) : fmaf(-part, sn, v * cs);
          }
          if (RELU2) { v = fmaxf(v, 0.f); v = v * v; }
          ((ushort*)Cv)[cOff + (long long)row * ldc + col] = f2bf(v);
        }
      }
}

// ---------------------------------------------------------------------------
// Fused flash attention (proven structure + setprio).
// ---------------------------------------------------------------------------
__global__ __launch_bounds__(256) void fattn_kernel(
    const ushort* __restrict__ Qg, const ushort* __restrict__ Kg,
    const ushort* __restrict__ Vg, ushort* __restrict__ Og)
{
  __shared__ char lds[73728];
  const int hb = blockIdx.y, pl = hb >> 3, h = hb & 7;
  const int q0 = blockIdx.x * 64;
  const int tid = threadIdx.x, lane = tid & 63, wv = tid >> 6;
  const int u = lane & 15, g = lane >> 4;
  const ushort* Qh = Qg + (size_t)pl * PLF + h * 128;
  const ushort* Kh = Kg + (size_t)pl * PLF + h * 128;
  const ushort* Vh = Vg + (size_t)pl * PLF + (size_t)(h * 128) * 512;
  ushort* Oh = Og + (size_t)pl * PLF + h * 128;

  short8 qf[4];
  const int qrow = q0 + wv * 16 + u;
#pragma unroll
  for (int dc = 0; dc < 4; ++dc)
    qf[dc] = *(const short8*)(Qh + (size_t)qrow * 1024 + dc * 32 + g * 8);

#define STAGE_KV(buf, kt)                                                     \
  {                                                                           \
    _Pragma("unroll")                                                         \
    for (int it = 0; it < 4; ++it) {                                          \
      const int off = tid * 16 + it * 4096;                                   \
      const int krow = off >> 8, kslot = (off >> 4) & 15;                     \
      GLOAD16(Kh + (size_t)((kt) * 64 + krow) * 1024 +                        \
                  ((kslot ^ ((krow & 7) << 1)) * 8),                          \
              &lds[(buf) * 16384] + off);                                     \
      const int vrow = off >> 7, vslot = (off >> 4) & 7;                      \
      GLOAD16(Vh + (size_t)vrow * 512 + (kt) * 64 + ((vslot ^ (vrow & 7)) * 8), \
              &lds[32768 + (buf) * 16384] + off);                             \
    }                                                                         \
  }

  f32x4 oacc[8];
#pragma unroll
  for (int i = 0; i < 8; ++i) oacc[i] = (f32x4){0.f, 0.f, 0.f, 0.f};
  float m_run = -3.0e38f, l_run = 0.f;

  STAGE_KV(0, 0);
  asm volatile("s_waitcnt vmcnt(0)" ::: "memory");
  __syncthreads();
  int cur = 0;
  for (int kt = 0; kt < 8; ++kt) {
    if (kt + 1 < 8) STAGE_KV(cur ^ 1, kt + 1);
    f32x4 sacc[4];
#pragma unroll
    for (int kn = 0; kn < 4; ++kn) sacc[kn] = (f32x4){0.f, 0.f, 0.f, 0.f};
    __builtin_amdgcn_s_setprio(1);
#pragma unroll
    for (int kn = 0; kn < 4; ++kn) {
      const int r = kn * 16 + u;
      const char* kb = &lds[cur * 16384] + r * 256;
#pragma unroll
      for (int dc = 0; dc < 4; ++dc) {
        short8 kf = *(const short8*)(kb + (((dc * 4 + g) ^ ((u & 7) << 1)) * 16));
        sacc[kn] = __builtin_amdgcn_mfma_f32_16x16x32_bf16(kf, qf[dc], sacc[kn], 0, 0, 0);
      }
    }
    __builtin_amdgcn_s_setprio(0);
    float pm = -3.0e38f;
#pragma unroll
    for (int kn = 0; kn < 4; ++kn)
#pragma unroll
      for (int r = 0; r < 4; ++r) {
        sacc[kn][r] *= 0.03125f;
        pm = fmaxf(pm, sacc[kn][r]);
      }
    pm = fmaxf(pm, __shfl_xor(pm, 16));
    pm = fmaxf(pm, __shfl_xor(pm, 32));
    const float m_new = fmaxf(m_run, pm);
    const float es = __expf(m_run - m_new);
    float psum = 0.f;
    uint pw[4][2];
#pragma unroll
    for (int kn = 0; kn < 4; ++kn) {
      float p0 = __expf(sacc[kn][0] - m_new);
      float p1 = __expf(sacc[kn][1] - m_new);
      float p2 = __expf(sacc[kn][2] - m_new);
      float p3 = __expf(sacc[kn][3] - m_new);
      psum += (p0 + p1) + (p2 + p3);
      pw[kn][0] = (uint)f2bf(p0) | ((uint)f2bf(p1) << 16);
      pw[kn][1] = (uint)f2bf(p2) | ((uint)f2bf(p3) << 16);
    }
    psum += __shfl_xor(psum, 16);
    psum += __shfl_xor(psum, 32);
    l_run = l_run * es + psum;
    m_run = m_new;
    char* pb = &lds[65536 + wv * 2048] + u * 128 + (g & 1) * 8;
#pragma unroll
    for (int kn = 0; kn < 4; ++kn)
      *(uint2*)(pb + (((2 * kn + (g >> 1)) ^ (u & 7)) * 16)) =
          make_uint2(pw[kn][0], pw[kn][1]);
    float es_o[4];
#pragma unroll
    for (int r = 0; r < 4; ++r) es_o[r] = __shfl(es, g * 4 + r);
#pragma unroll
    for (int nd = 0; nd < 8; ++nd)
#pragma unroll
      for (int r = 0; r < 4; ++r) oacc[nd][r] *= es_o[r];
    const char* prd = &lds[65536 + wv * 2048] + u * 128;
    short8 pf[2];
#pragma unroll
    for (int kc = 0; kc < 2; ++kc)
      pf[kc] = *(const short8*)(prd + (((kc * 4 + g) ^ (u & 7)) * 16));
    __builtin_amdgcn_s_setprio(1);
#pragma unroll
    for (int nd = 0; nd < 8; ++nd) {
      const int vr = nd * 16 + u;
      const char* vb = &lds[32768 + cur * 16384] + vr * 128;
#pragma unroll
      for (int kc = 0; kc < 2; ++kc) {
        short8 vf = *(const short8*)(vb + (((kc * 4 + g) ^ (u & 7)) * 16));
        oacc[nd] = __builtin_amdgcn_mfma_f32_16x16x32_bf16(pf[kc], vf, oacc[nd], 0, 0, 0);
      }
    }
    __builtin_amdgcn_s_setprio(0);
    asm volatile("s_waitcnt vmcnt(0)" ::: "memory");
    __syncthreads();
    cur ^= 1;
  }
#undef STAGE_KV
  const float inv_l = 1.f / l_run;
  float inv_o[4];
#pragma unroll
  for (int r = 0; r < 4; ++r) inv_o[r] = __shfl(inv_l, g * 4 + r);
#pragma unroll
  for (int nd = 0; nd < 8; ++nd)
#pragma unroll
    for (int r = 0; r < 4; ++r) {
      const int row = q0 + wv * 16 + g * 4 + r;
      Oh[(size_t)row * 1024 + nd * 16 + u] = f2bf(oacc[nd][r] * inv_o[r]);
    }
}

// ---------------- fp32 -> bf16 weight conversion (8 elem/thread) ------------
__global__ __launch_bounds__(256) void cvt_kernel(
    const float4* __restrict__ s, short8* __restrict__ d)
{
  const int i = blockIdx.x * 256 + threadIdx.x;
  const float4 a = s[2 * i], b = s[2 * i + 1];
  short8 h;
  h[0] = (short)f2bf(a.x); h[1] = (short)f2bf(a.y);
  h[2] = (short)f2bf(a.z); h[3] = (short)f2bf(a.w);
  h[4] = (short)f2bf(b.x); h[5] = (short)f2bf(b.y);
  h[6] = (short)f2bf(b.z); h[7] = (short)f2bf(b.w);
  d[i] = h;
}

// ---------------------------------------------------------------------------
// conv 3x3 SAME on [512 w][F f] planes; 2 w-rows x 8 f x 4 co per thread.
// ---------------------------------------------------------------------------
template <int CIN>
__global__ __launch_bounds__(256) void conv4c_kernel(
    const ushort* __restrict__ in, const float* __restrict__ wt,
    const float* __restrict__ bias, ushort* __restrict__ outp, int log2F)
{
  const int idx = blockIdx.x * 256 + threadIdx.x;
  const int F8m = (1 << (log2F - 3)) - 1;
  const int f8 = idx & F8m;
  const int wp2 = (idx >> (log2F - 3)) & 255;
  const int bb = idx >> (log2F + 5);
  const int w = wp2 * 2;
  const int f0 = f8 << 3;
  float acc[2][4][8];
#pragma unroll
  for (int co = 0; co < 4; ++co) {
    const float bv = bias[co];
#pragma unroll
    for (int j = 0; j < 8; ++j) { acc[0][co][j] = bv; acc[1][co][j] = bv; }
  }
  const bool lok = f8 > 0, rok = f8 < F8m;
#pragma unroll
  for (int ci = 0; ci < CIN; ++ci) {
    const ushort* base = in + (((size_t)(bb * CIN + ci)) << (log2F + 9));
#pragma unroll
    for (int rr = 0; rr < 4; ++rr) {
      const int wr = w - 1 + rr;
      if (wr < 0 || wr > 511) continue;
      const ushort* rp = base + ((size_t)wr << log2F) + f0;
      const short8 cen = *(const short8*)rp;
      float xv[10];
      xv[0] = lok ? bf2f(rp[-1]) : 0.f;
#pragma unroll
      for (int j = 0; j < 8; ++j) xv[j + 1] = bf2f((ushort)cen[j]);
      xv[9] = rok ? bf2f(rp[8]) : 0.f;
#pragma unroll
      for (int co = 0; co < 4; ++co) {
        const float* wp = wt + (co * CIN + ci) * 9;
        if (rr <= 2) {
          const float k0 = wp[rr], k1 = wp[3 + rr], k2 = wp[6 + rr];
#pragma unroll
          for (int j = 0; j < 8; ++j)
            acc[0][co][j] += k0 * xv[j] + k1 * xv[j + 1] + k2 * xv[j + 2];
        }
        if (rr >= 1) {
          const float k0 = wp[rr - 1], k1 = wp[2 + rr], k2 = wp[5 + rr];
#pragma unroll
          for (int j = 0; j < 8; ++j)
            acc[1][co][j] += k0 * xv[j] + k1 * xv[j + 1] + k2 * xv[j + 2];
        }
      }
    }
  }
#pragma unroll
  for (int wo = 0; wo < 2; ++wo)
#pragma unroll
    for (int co = 0; co < 4; ++co) {
      short8 o;
#pragma unroll
      for (int j = 0; j < 8; ++j) o[j] = (short)f2bf(acc[wo][co][j]);
      *(short8*)(outp + (((size_t)(bb * 4 + co)) << (log2F + 9)) +
                 ((size_t)(w + wo) << log2F) + f0) = o;
    }
}

// ---------------------------------------------------------------------------
// q/k/v merged conv: reads XN once, computes 12 output channels.
// ---------------------------------------------------------------------------
__global__ __launch_bounds__(256) void conv12c_kernel(
    const ushort* __restrict__ in,
    const float* __restrict__ wq, const float* __restrict__ wk, const float* __restrict__ wv,
    const float* __restrict__ bq, const float* __restrict__ bk, const float* __restrict__ bv,
    ushort* __restrict__ outp, int nPl)
{
  const int idx = blockIdx.x * 256 + threadIdx.x;
  const int f8 = idx & 127;
  const int w = (idx >> 7) & 511;
  const int bb = idx >> 16;
  const int f0 = f8 << 3;
  const float* wsel[3] = {wq, wk, wv};
  float acc[12][8];
#pragma unroll
  for (int co = 0; co < 4; ++co) {
    const float b0 = bq[co], b1 = bk[co], b2 = bv[co];
#pragma unroll
    for (int j = 0; j < 8; ++j) {
      acc[co][j] = b0; acc[4 + co][j] = b1; acc[8 + co][j] = b2;
    }
  }
  const bool lok = f8 > 0, rok = f8 < 127;
#pragma unroll
  for (int ci = 0; ci < 4; ++ci) {
    const ushort* base = in + (((size_t)(bb * 4 + ci)) << 19);
#pragma unroll
    for (int dxw = 0; dxw < 3; ++dxw) {
      const int w2 = w + dxw - 1;
      if (w2 < 0 || w2 > 511) continue;
      const ushort* rp = base + ((size_t)w2 << 10) + f0;
      const short8 cen = *(const short8*)rp;
      float xv[10];
      xv[0] = lok ? bf2f(rp[-1]) : 0.f;
#pragma unroll
      for (int j = 0; j < 8; ++j) xv[j + 1] = bf2f((ushort)cen[j]);
      xv[9] = rok ? bf2f(rp[8]) : 0.f;
#pragma unroll
      for (int pj = 0; pj < 3; ++pj)
#pragma unroll
        for (int co = 0; co < 4; ++co) {
          const float* wp = wsel[pj] + (co * 4 + ci) * 9;
          const float k0 = wp[dxw], k1 = wp[3 + dxw], k2 = wp[6 + dxw];
#pragma unroll
          for (int j = 0; j < 8; ++j)
            acc[pj * 4 + co][j] += k0 * xv[j] + k1 * xv[j + 1] + k2 * xv[j + 2];
        }
    }
  }
#pragma unroll
  for (int pj = 0; pj < 3; ++pj)
#pragma unroll
    for (int co = 0; co < 4; ++co) {
      short8 o;
#pragma unroll
      for (int j = 0; j < 8; ++j) o[j] = (short)f2bf(acc[pj * 4 + co][j]);
      *(short8*)(outp + (((size_t)(pj * nPl + bb * 4 + co)) << 19) +
                 ((size_t)w << 10) + f0) = o;
    }
}

// ---------------- layernorm over f (rows of 1024), H fp32 -> XN bf16 --------
__global__ __launch_bounds__(256) void ln_kernel(
    const float* __restrict__ H, const float* __restrict__ gam,
    const float* __restrict__ bet, ushort* __restrict__ XN)
{
  const int wid = threadIdx.x >> 6, lane = threadIdx.x & 63;
  const int row = blockIdx.x * 4 + wid;
  const int c = (row >> 9) & 3;
  const float* xp = H + (size_t)row * 1024;
  float4 v[4];
  float s = 0.f, q = 0.f;
#pragma unroll
  for (int p = 0; p < 4; ++p) {
    v[p] = *(const float4*)(xp + p * 256 + lane * 4);
    s += v[p].x + v[p].y + v[p].z + v[p].w;
    q += v[p].x * v[p].x + v[p].y * v[p].y + v[p].z * v[p].z + v[p].w * v[p].w;
  }
#pragma unroll
  for (int o = 32; o > 0; o >>= 1) { s += __shfl_xor(s, o); q += __shfl_xor(q, o); }
  const float mu = s * (1.f / 1024.f);
  const float var = q * (1.f / 1024.f) - mu * mu;
  const float rs = rsqrtf(var + 1e-5f);
  ushort* op = XN + (size_t)row * 1024;
  const float* gp = gam + c * 1024;
  const float* bp = bet + c * 1024;
#pragma unroll
  for (int p = 0; p < 4; ++p) {
    const int f = p * 256 + lane * 4;
    float4 g4 = *(const float4*)(gp + f);
    float4 b4 = *(const float4*)(bp + f);
    ushort4 o4;
    o4.x = f2bf((v[p].x - mu) * rs * g4.x + b4.x);
    o4.y = f2bf((v[p].y - mu) * rs * g4.y + b4.y);
    o4.z = f2bf((v[p].z - mu) * rs * g4.z + b4.z);
    o4.w = f2bf((v[p].w - mu) * rs * g4.w + b4.w);
    *(ushort4*)(op + f) = o4;
  }
}

// ---- transpose-in: x fp32 [f][w] -> XT bf16 [w][f]; also copy x -> out -----
__global__ __launch_bounds__(256) void tin_kernel(
    const float* __restrict__ x, ushort* __restrict__ XT,
    float* __restrict__ outp, int planeOff)
{
  __shared__ float t[32][33];
  const int f0 = blockIdx.x * 32, w0 = blockIdx.y * 32;
  const int z = blockIdx.z;
  const int tx = threadIdx.x & 31, ty = threadIdx.x >> 5;
  const int gpl = planeOff + z;
  const int b = gpl >> 3, ch = gpl & 7;
  const float* src = x + (size_t)gpl * PLF;
  float* dst0 = outp + (size_t)(b * 12 + ch) * PLF;
#pragma unroll
  for (int r = 0; r < 32; r += 8) {
    const size_t off = (size_t)(f0 + r + ty) * 512 + w0 + tx;
    const float v = src[off];
    t[r + ty][tx] = v;
    dst0[off] = v;
  }
  __syncthreads();
  ushort* dst = XT + (size_t)z * PLF;
#pragma unroll
  for (int r = 0; r < 32; r += 8) dst[(size_t)(w0 + r + ty) * 1024 + f0 + tx] = f2bf(t[tx][r + ty]);
}

// ---------------- transpose-out: H fp32 [w][f] -> out[b][8+c][f][w] ---------
__global__ __launch_bounds__(256) void tout_kernel(
    const float* __restrict__ H, float* __restrict__ out, int b0)
{
  __shared__ float t[32][33];
  const int w0 = blockIdx.x * 32, f0 = blockIdx.y * 32;
  const int p = blockIdx.z;
  const int b = b0 + (p >> 2), c = p & 3;
  const int tx = threadIdx.x & 31, ty = threadIdx.x >> 5;
  const float* src = H + (size_t)p * PLF;
#pragma unroll
  for (int r = 0; r < 32; r += 8) t[r + ty][tx] = src[(size_t)(w0 + r + ty) * 1024 + f0 + tx];
  __syncthreads();
  float* dst = out + (size_t)(b * 12 + 8 + c) * PLF;
#pragma unroll
  for (int r = 0; r < 32; r += 8) dst[(size_t)(f0 + r + ty) * 512 + w0 + tx] = t[tx][r + ty];
}

// ---------------------------------------------------------------------------
extern "C" void kernel_launch(void* const* d_in, const int* in_sizes, int n_in,
                              void* d_out, int out_size, void* d_ws, size_t ws_size,
                              hipStream_t stream)
{
  const float* x        = (const float*)d_in[0];
  const float* embed_cw = (const float*)d_in[1];
  const float* embed_cb = (const float*)d_in[2];
  const float* embed_pw = (const float*)d_in[3];
  const float* n1g      = (const float*)d_in[4];
  const float* n1b      = (const float*)d_in[5];
  const float* q_cw     = (const float*)d_in[6];
  const float* q_cb     = (const float*)d_in[7];
  const float* q_pw     = (const float*)d_in[8];
  const float* k_cw     = (const float*)d_in[9];
  const float* k_cb     = (const float*)d_in[10];
  const float* k_pw     = (const float*)d_in[11];
  const float* v_cw     = (const float*)d_in[12];
  const float* v_cb     = (const float*)d_in[13];
  const float* v_pw     = (const float*)d_in[14];
  const float* o_cw     = (const float*)d_in[15];
  const float* o_cb     = (const float*)d_in[16];
  const float* o_pw     = (const float*)d_in[17];
  const float* n2g      = (const float*)d_in[18];
  const float* n2b      = (const float*)d_in[19];
  const float* f1_cw    = (const float*)d_in[20];
  const float* f1_cb    = (const float*)d_in[21];
  const float* f1_pw    = (const float*)d_in[22];
  const float* f2_cw    = (const float*)d_in[23];
  const float* f2_cb    = (const float*)d_in[24];
  const float* f2_pw    = (const float*)d_in[25];
  float* out = (float*)d_out;

  const size_t perB = 50331648ull;
  const int N = (ws_size >= 4 * perB) ? 4 : (ws_size >= 2 * perB) ? 2 : 1;
  const int nP = 4 * N;

  // layout: Hf | XT | XN | Qb | Kb | CT | Vb | SfPb
  char* base = (char*)d_ws;
  float*  Hf = (float*)base;
  ushort* XT = (ushort*)(base + (size_t)N * 8388608);
  ushort* XN = (ushort*)((char*)XT + (size_t)N * 8388608);
  ushort* Qb = (ushort*)((char*)XN + (size_t)N * 4194304);
  ushort* Kb = (ushort*)((char*)Qb + (size_t)N * 4194304);
  ushort* CT = (ushort*)((char*)Kb + (size_t)N * 4194304);
  ushort* Vb = (ushort*)((char*)CT + (size_t)N * 4194304);
  ushort* SfPb = (ushort*)((char*)Vb + (size_t)N * 4194304);
  ushort* CT3 = SfPb;
  ushort* W8  = SfPb;
  ushort* WQK = XT;
  ushort* MID = XT;
  ushort* f1w = Vb;
  ushort* F2C = Vb;
  ushort* f2w = XT;

  const long long W1 = 1048576;
  const long long W4 = 4194304;
  const long long M1 = 2097152;
  const long long CH3 = (long long)nP * PLF;
  const int GCc1 = N * 128;
  const int GCc4 = N * 512;
  const int GC12 = N * 256;

  for (int b0 = 0; b0 < 4; b0 += N) {
    // --- input transpose + x copy to out ---
    tin_kernel<<<dim3(32, 16, 8 * N), 256, 0, stream>>>(x, XT, out, b0 * 8);
    // --- embed ---
    conv4c_kernel<8><<<GCc1, 256, 0, stream>>>(XT, embed_cw, embed_cb, CT, 10);
    cvt_kernel<<<2048, 256, 0, stream>>>((const float4*)embed_pw, (short8*)W8);
    mm2_kernel<0, 0, 0, 1, 0><<<dim3(4, 4, nP), 512, 0, stream>>>(
        CT, W8, Hf, 1024, 1024, 1024, 1024,
        1, 1, PLF, 0, 4, 4, 0, W1, 1, 1, PLF, 0, 1.f);
    // --- LN1 ---
    ln_kernel<<<nP * 128, 256, 0, stream>>>(Hf, n1g, n1b, XN);
    // --- merged q/k/v conv ---
    conv12c_kernel<<<GC12, 256, 0, stream>>>(XN, q_cw, k_cw, v_cw,
                                             q_cb, k_cb, v_cb, CT3, nP);
    // --- q+k projection (RoPE fused into epilogue) ---
    if (N >= 2) {
      cvt_kernel<<<2048, 256, 0, stream>>>((const float4*)q_pw, (short8*)WQK);
      cvt_kernel<<<2048, 256, 0, stream>>>((const float4*)k_pw, (short8*)(WQK) + 524288);
      mm2_kernel<1, 0, 0, 1, 1><<<dim3(4, 4, 2 * nP), 512, 0, stream>>>(
          CT3, WQK, Qb, 1024, 1024, 1024, 1024,
          1, 1, PLF, 0, nP, 4, 4 * W1, W1, 1, 1, PLF, 0, 1.f);
    } else {
      mm_kernel<1, 0, 0, 1, 1, 1><<<dim3(8, 4, nP), 256, 0, stream>>>(
          CT3, q_pw, Qb, 1024, 1024, 1024, 1024,
          1, 1, PLF, 0, 4, 4, 0, W1, 1, 1, PLF, 0, 1.f);
      mm_kernel<1, 0, 0, 1, 1, 1><<<dim3(8, 4, nP), 256, 0, stream>>>(
          CT3 + CH3, k_pw, Kb, 1024, 1024, 1024, 1024,
          1, 1, PLF, 0, 4, 4, 0, W1, 1, 1, PLF, 0, 1.f);
    }
    // --- v projection (V stored [f][w]) ---
    cvt_kernel<<<2048, 256, 0, stream>>>((const float4*)v_pw, (short8*)W8);
    mm2_kernel<1, 0, 0, 0, 0><<<dim3(2, 8, nP), 512, 0, stream>>>(
        W8, CT3 + 2 * CH3, Vb, 1024, 1024, 1024, 512,
        4, 4, 0, W1, 1, 1, PLF, 0, 1, 1, PLF, 0, 1.f);
    // --- fused flash attention (O overwrites Q) ---
    fattn_kernel<<<dim3(8, nP * 8), 256, 0, stream>>>(Qb, Kb, Vb, Qb);
    // --- o projection (accumulate into H) ---
    conv4c_kernel<4><<<GCc1, 256, 0, stream>>>(Qb, o_cw, o_cb, CT, 10);
    cvt_kernel<<<2048, 256, 0, stream>>>((const float4*)o_pw, (short8*)W8);
    mm2_kernel<0, 1, 0, 1, 0><<<dim3(4, 4, nP), 512, 0, stream>>>(
        CT, W8, Hf, 1024, 1024, 1024, 1024,
        1, 1, PLF, 0, 4, 4, 0, W1, 1, 1, PLF, 0, 1.f);
    // --- LN2 ---
    ln_kernel<<<nP * 128, 256, 0, stream>>>(Hf, n2g, n2b, XN);
    // --- ffn1 (+fused squared relu) ---
    conv4c_kernel<4><<<GCc1, 256, 0, stream>>>(XN, f1_cw, f1_cb, CT, 10);
    if (N >= 2) {
      cvt_kernel<<<8192, 256, 0, stream>>>((const float4*)f1_pw, (short8*)f1w);
      mm2_kernel<1, 0, 1, 1, 0><<<dim3(16, 4, nP), 512, 0, stream>>>(
          CT, f1w, MID, 1024, 1024, 1024, 4096,
          1, 1, PLF, 0, 4, 4, 0, W4, 1, 1, M1, 0, 1.f);
    } else {
      mm_kernel<1, 0, 1, 1, 1, 0><<<dim3(32, 4, nP), 256, 0, stream>>>(
          CT, f1_pw, MID, 1024, 1024, 1024, 4096,
          1, 1, PLF, 0, 4, 4, 0, W4, 1, 1, M1, 0, 1.f);
    }
    // --- ffn2 conv (F=4096) then pw accumulate into H ---
    conv4c_kernel<4><<<GCc4, 256, 0, stream>>>(MID, f2_cw, f2_cb, F2C, 12);
    if (N >= 2) {
      cvt_kernel<<<8192, 256, 0, stream>>>((const float4*)f2_pw, (short8*)f2w);
      mm2_kernel<0, 1, 0, 1, 0><<<dim3(4, 4, nP), 512, 0, stream>>>(
          F2C, f2w, Hf, 4096, 4096, 4096, 1024,
          1, 1, M1, 0, 4, 4, 0, W4, 1, 1, PLF, 0, 1.f);
    } else {
      mm_kernel<0, 1, 0, 1, 1, 0><<<dim3(8, 4, nP), 256, 0, stream>>>(
          F2C, f2_pw, Hf, 4096, 4096, 4096, 1024,
          1, 1, M1, 0, 4, 4, 0, W4, 1, 1, PLF, 0, 1.f);
    }
    // --- output transpose ---
    tout_kernel<<<dim3(16, 32, nP), 256, 0, stream>>>(Hf, out, b0);
  }
}